// Round 12
// baseline (251.533 us; speedup 1.0000x reference)
//
#include <hip/hip_runtime.h>
#include <hip/hip_bf16.h>
#include <math.h>

#define NN 50000
#define EE 500000
#define ETOT (EE + NN)
#define NG 64

typedef __attribute__((ext_vector_type(8))) short short8v;   // 8 bf16 (4 VGPRs)
typedef __attribute__((ext_vector_type(4))) float float4v;   // 4 fp32 acc
typedef __attribute__((ext_vector_type(2))) float float2v;

__device__ __forceinline__ float bf2f(unsigned short u) {
    unsigned int v = ((unsigned int)u) << 16;
    return __builtin_bit_cast(float, v);
}
__device__ __forceinline__ unsigned short f2bf(float f) {
    __hip_bfloat16 h = __float2bfloat16(f);
    return *(unsigned short*)&h;
}
// hardware fp8 e4m3 converts (gfx950 native)
__device__ __forceinline__ unsigned char f2fp8_hw(float f) {
    return (unsigned char)(__builtin_amdgcn_cvt_pk_fp8_f32(f, f, 0, false) & 0xff);
}

// ---------------- histogram of dst + per-graph node counts ----------------
__global__ void k_hist(const int* __restrict__ ei, const int* __restrict__ batch,
                       int* __restrict__ counts, int* __restrict__ gcount) {
    int t = blockIdx.x * 256 + threadIdx.x;
    if (t < ETOT) {
        int dst = (t < EE) ? ei[EE + t] : (t - EE);
        atomicAdd(counts + dst, 1);
    }
    if (t < NN) {
        int g = batch[t];
        int g0 = __shfl(g, 0);
        bool same = (g == g0);
        unsigned long long m = __ballot(same);
        if (same) {
            if ((threadIdx.x & 63) == (__ffsll((long long)m) - 1))
                atomicAdd(gcount + g0, (int)__popcll(m));
        } else {
            atomicAdd(gcount + g, 1);
        }
    }
}

// ---------------- exclusive scan counts -> indptr (+ seed cursor) ---------
__global__ void k_scan(const int* __restrict__ counts, int* __restrict__ indptr,
                       int* __restrict__ cursor) {
    __shared__ int wsum[16];
    __shared__ int carry_s;
    int tid = threadIdx.x;
    int lane = tid & 63;
    int w = tid >> 6;
    if (tid == 0) carry_s = 0;
    __syncthreads();
    for (int base = 0; base < NN; base += 4096) {
        int i = base + tid * 4;
        int v0 = 0, v1 = 0, v2 = 0, v3 = 0;
        if (i + 3 < NN) {
            int4 vv = *(const int4*)&counts[i];
            v0 = vv.x; v1 = vv.y; v2 = vv.z; v3 = vv.w;
        } else {
            if (i < NN) v0 = counts[i];
            if (i + 1 < NN) v1 = counts[i + 1];
            if (i + 2 < NN) v2 = counts[i + 2];
            if (i + 3 < NN) v3 = counts[i + 3];
        }
        int tot = v0 + v1 + v2 + v3;
        int s = tot;
#pragma unroll
        for (int off = 1; off < 64; off <<= 1) {
            int u = __shfl_up(s, off);
            if (lane >= off) s += u;
        }
        if (lane == 63) wsum[w] = s;
        __syncthreads();
        if (w == 0) {
            int t2 = (lane < 16) ? wsum[lane] : 0;
#pragma unroll
            for (int off = 1; off < 16; off <<= 1) {
                int u = __shfl_up(t2, off);
                if (lane >= off) t2 += u;
            }
            if (lane < 16) wsum[lane] = t2;
        }
        __syncthreads();
        int wpre = (w == 0) ? 0 : wsum[w - 1];
        int incl = s + wpre;
        int carry = carry_s;
        int e = carry + incl - tot;
        if (i < NN)     { indptr[i] = e;                cursor[i] = e; }
        if (i + 1 < NN) { int q = e + v0;               indptr[i+1] = q; cursor[i+1] = q; }
        if (i + 2 < NN) { int q = e + v0 + v1;          indptr[i+2] = q; cursor[i+2] = q; }
        if (i + 3 < NN) { int q = e + v0 + v1 + v2;     indptr[i+3] = q; cursor[i+3] = q; }
        __syncthreads();
        if (tid == 1023) carry_s = carry + incl;
        __syncthreads();
    }
    if (tid == 0) indptr[NN] = carry_s;
}

// ---------------- W1 -> bf16 ----------------------------------------------
__global__ void k_cvtw(const float* __restrict__ W1, unsigned short* __restrict__ wb) {
    int t = blockIdx.x * 256 + threadIdx.x;
    if (t >= 256 * 128) return;
    wb[t] = f2bf(W1[t]);
}

// ---------------- x -> bf16, 8 elems/thread -------------------------------
__global__ void k_cvtx(const float* __restrict__ x, unsigned short* __restrict__ xb) {
    int t = blockIdx.x * 256 + threadIdx.x;
    if (t >= NN * 128 / 8) return;
    float4 a = *(const float4*)&x[(size_t)t * 8];
    float4 b = *(const float4*)&x[(size_t)t * 8 + 4];
    float f[8] = {a.x, a.y, a.z, a.w, b.x, b.y, b.z, b.w};
    short8v vh;
#pragma unroll
    for (int j = 0; j < 8; ++j) vh[j] = (short)f2bf(f[j]);
    *(short8v*)&xb[(size_t)t * 8] = vh;
}

// ---------------- GEMM1 via bf16 MFMA + fused alpha logits ----------------
__global__ __launch_bounds__(256) void k_gemm1(const unsigned short* __restrict__ xb,
                                               const unsigned short* __restrict__ wb,
                                               const float* __restrict__ att_s,
                                               const float* __restrict__ att_d,
                                               unsigned char* __restrict__ h1f8,
                                               float* __restrict__ alpha_s,
                                               float* __restrict__ alpha_d) {
    int w = threadIdx.x >> 6;
    int l = threadIdx.x & 63;
    int bm0 = blockIdx.x * 32;
    int i16 = l & 15;
    int kb = (l >> 4) * 8;
    int colb = w * 64;

    short8v a[2][4];
#pragma unroll
    for (int mi = 0; mi < 2; ++mi) {
        int r = bm0 + mi * 16 + i16;
#pragma unroll
        for (int k = 0; k < 4; ++k) {
            if (r < NN) a[mi][k] = *(const short8v*)&xb[(size_t)r * 128 + k * 32 + kb];
            else        a[mi][k] = (short8v){0,0,0,0,0,0,0,0};
        }
    }

    float4v acc[2][4];
#pragma unroll
    for (int mi = 0; mi < 2; ++mi)
#pragma unroll
        for (int ni = 0; ni < 4; ++ni)
            acc[mi][ni] = (float4v){0.f, 0.f, 0.f, 0.f};

#pragma unroll
    for (int k = 0; k < 4; ++k) {
#pragma unroll
        for (int ni = 0; ni < 4; ++ni) {
            short8v b = *(const short8v*)&wb[(size_t)(colb + ni * 16 + i16) * 128 + k * 32 + kb];
            acc[0][ni] = __builtin_amdgcn_mfma_f32_16x16x32_bf16(a[0][k], b, acc[0][ni], 0, 0, 0);
            acc[1][ni] = __builtin_amdgcn_mfma_f32_16x16x32_bf16(a[1][k], b, acc[1][ni], 0, 0, 0);
        }
    }

    // epilogue: fp8 store + fused alpha logits (head = w)
    int drb = (l >> 4) * 4;
    int dc = l & 15;
    float asw[4], adw[4];
#pragma unroll
    for (int ni = 0; ni < 4; ++ni) {
        asw[ni] = att_s[colb + ni * 16 + dc];
        adw[ni] = att_d[colb + ni * 16 + dc];
    }
#pragma unroll
    for (int mi = 0; mi < 2; ++mi) {
#pragma unroll
        for (int r = 0; r < 4; ++r) {
            int row = bm0 + mi * 16 + drb + r;
            float s = 0.f, d = 0.f;
#pragma unroll
            for (int ni = 0; ni < 4; ++ni) {
                float v = acc[mi][ni][r];
                s += v * asw[ni];
                d += v * adw[ni];
                if (row < NN)
                    h1f8[(size_t)row * 256 + colb + ni * 16 + dc] = f2fp8_hw(v);
            }
#pragma unroll
            for (int m = 8; m >= 1; m >>= 1) {
                s += __shfl_xor(s, m);
                d += __shfl_xor(d, m);
            }
            if (dc == 0 && row < NN) {
                alpha_s[row * 4 + w] = s;
                alpha_d[row * 4 + w] = d;
            }
        }
    }
}

// ---------------- bucket fill + edge softmax weights (bf16 x4) ------------
// Edge-parallel: compute exp(leaky(alpha_s[src]+alpha_d[dst])) for all 4
// heads ONCE per edge (vs 16x redundant per-lane in the gather).
__global__ void k_fill(const int* __restrict__ ei, int* __restrict__ cursor,
                       const float* __restrict__ als, const float* __restrict__ ald,
                       int* __restrict__ srcs, ushort4* __restrict__ ee1) {
    int t = blockIdx.x * 256 + threadIdx.x;
    if (t >= ETOT) return;
    int src = (t < EE) ? ei[t] : (t - EE);
    int dst = (t < EE) ? ei[EE + t] : (t - EE);
    int p = atomicAdd(cursor + dst, 1);
    srcs[p] = src;
    float4 as = *(const float4*)&als[src * 4];
    float4 ad = *(const float4*)&ald[dst * 4];
    float e0 = as.x + ad.x, e1 = as.y + ad.y, e2 = as.z + ad.z, e3 = as.w + ad.w;
    e0 = e0 > 0.f ? e0 : 0.2f * e0;
    e1 = e1 > 0.f ? e1 : 0.2f * e1;
    e2 = e2 > 0.f ? e2 : 0.2f * e2;
    e3 = e3 > 0.f ? e3 : 0.2f * e3;
    ushort4 ev;
    ev.x = f2bf(__expf(e0));
    ev.y = f2bf(__expf(e1));
    ev.z = f2bf(__expf(e2));
    ev.w = f2bf(__expf(e3));
    ee1[p] = ev;
}

// ---------------- gather-aggregate layer 1 + softmax + bias + ELU ---------
// one wave per dst node; lane l owns channels 4l..4l+3 (head = l>>4).
// Pre-computed bf16 edge weights: per edge-lane = 1x 2B load + 1x 4B load +
// 2 cvt_pk + 5 FMA. No exp, no alpha gather.
__global__ void k_gather1(const int* __restrict__ indptr, const int* __restrict__ srcs,
                          const unsigned short* __restrict__ ee1,
                          const unsigned char* __restrict__ h1f8, const float* __restrict__ b1,
                          unsigned short* __restrict__ h1o) {
    int wid = (blockIdx.x * 256 + threadIdx.x) >> 6;
    int l = threadIdx.x & 63;
    if (wid >= NN) return;
    int p0 = indptr[wid], p1 = indptr[wid + 1];
    int head = l >> 4;
    float acc0 = 0.f, acc1 = 0.f, acc2 = 0.f, acc3 = 0.f, dsum = 0.f;
    int p = p0;
    for (; p + 1 < p1; p += 2) {
        int sA = srcs[p], sB = srcs[p + 1];
        float wA = bf2f(ee1[p * 4 + head]);
        float wB = bf2f(ee1[(p + 1) * 4 + head]);
        unsigned int hvA = *(const unsigned int*)&h1f8[(size_t)sA * 256 + l * 4];
        unsigned int hvB = *(const unsigned int*)&h1f8[(size_t)sB * 256 + l * 4];
        float2v loA = __builtin_amdgcn_cvt_pk_f32_fp8(hvA, false);
        float2v hiA = __builtin_amdgcn_cvt_pk_f32_fp8(hvA, true);
        float2v loB = __builtin_amdgcn_cvt_pk_f32_fp8(hvB, false);
        float2v hiB = __builtin_amdgcn_cvt_pk_f32_fp8(hvB, true);
        dsum += wA + wB;
        acc0 += wA * loA.x + wB * loB.x;
        acc1 += wA * loA.y + wB * loB.y;
        acc2 += wA * hiA.x + wB * hiB.x;
        acc3 += wA * hiA.y + wB * hiB.y;
    }
    if (p < p1) {
        int s = srcs[p];
        float w = bf2f(ee1[p * 4 + head]);
        unsigned int hv = *(const unsigned int*)&h1f8[(size_t)s * 256 + l * 4];
        float2v lo = __builtin_amdgcn_cvt_pk_f32_fp8(hv, false);
        float2v hi = __builtin_amdgcn_cvt_pk_f32_fp8(hv, true);
        dsum += w;
        acc0 += w * lo.x;
        acc1 += w * lo.y;
        acc2 += w * hi.x;
        acc3 += w * hi.y;
    }
    float inv = 1.0f / dsum;
    float4 bv = *(const float4*)&b1[l * 4];
    float o0 = acc0 * inv + bv.x;
    float o1 = acc1 * inv + bv.y;
    float o2 = acc2 * inv + bv.z;
    float o3 = acc3 * inv + bv.w;
    o0 = o0 > 0.f ? o0 : expm1f(o0);
    o1 = o1 > 0.f ? o1 : expm1f(o1);
    o2 = o2 > 0.f ? o2 : expm1f(o2);
    o3 = o3 > 0.f ? o3 : expm1f(o3);
    ushort4 ov;
    ov.x = f2bf(o0); ov.y = f2bf(o1); ov.z = f2bf(o2); ov.w = f2bf(o3);
    *(ushort4*)&h1o[(size_t)wid * 256 + l * 4] = ov;
}

// ---------------- GEMM2 (wave/node) + attention logits layer 2 ------------
__global__ void k_gemm2a(const unsigned short* __restrict__ h1o, const float* __restrict__ W2,
                         const float* __restrict__ as2v, const float* __restrict__ ad2v,
                         float* __restrict__ h2lin, float* __restrict__ alpha_s2,
                         float* __restrict__ alpha_d2) {
    int wid = (blockIdx.x * 256 + threadIdx.x) >> 6;
    int l = threadIdx.x & 63;
    if (wid >= NN) return;
    ushort4 hv = *(const ushort4*)&h1o[(size_t)wid * 256 + l * 4];
    float h0 = bf2f(hv.x), h1_ = bf2f(hv.y), h2 = bf2f(hv.z), h3 = bf2f(hv.w);
    float t[10];
#pragma unroll
    for (int o = 0; o < 10; ++o) {
        float4 wv = *(const float4*)&W2[o * 256 + l * 4];
        t[o] = h0 * wv.x + h1_ * wv.y + h2 * wv.z + h3 * wv.w;
    }
#pragma unroll
    for (int m = 32; m > 0; m >>= 1) {
#pragma unroll
        for (int o = 0; o < 10; ++o) t[o] += __shfl_xor(t[o], m);
    }
    if (l == 0) {
        float as = 0.f, ad = 0.f;
#pragma unroll
        for (int o = 0; o < 10; ++o) {
            h2lin[(size_t)wid * 10 + o] = t[o];
            as += t[o] * as2v[o];
            ad += t[o] * ad2v[o];
        }
        alpha_s2[wid] = as;
        alpha_d2[wid] = ad;
    }
}

// ---------------- gather layer 2 + softmax + bias + fused mean-pool -------
__global__ void k_g2pool(const int* __restrict__ indptr, const int* __restrict__ srcs,
                         const float* __restrict__ als2, const float* __restrict__ ald2,
                         const float* __restrict__ h2lin, const float* __restrict__ b2,
                         const int* __restrict__ batch, float* __restrict__ pooled) {
    int t = blockIdx.x * 256 + threadIdx.x;
    bool valid = t < NN;
    float acc[10] = {};
    int g = -1;
    if (valid) {
        int p0 = indptr[t], p1 = indptr[t + 1];
        float adt = ald2[t];
        float dsum = 0.f;
        for (int p = p0; p < p1; ++p) {
            int s = srcs[p];
            float v = als2[s] + adt;
            v = v > 0.f ? v : 0.2f * v;
            float w = __expf(v);
            dsum += w;
            const float* hr = &h2lin[(size_t)s * 10];
#pragma unroll
            for (int c = 0; c < 10; ++c) acc[c] += w * hr[c];
        }
        float inv = 1.0f / dsum;
#pragma unroll
        for (int c = 0; c < 10; ++c) acc[c] = acc[c] * inv + b2[c];
        g = batch[t];
    }
    int g0 = __shfl(g, 0);
    bool uni = __all((!valid) || (g == g0));
    if (uni) {
        if (g0 >= 0) {
#pragma unroll
            for (int m = 32; m > 0; m >>= 1) {
#pragma unroll
                for (int c = 0; c < 10; ++c) acc[c] += __shfl_xor(acc[c], m);
            }
            if ((threadIdx.x & 63) == 0) {
#pragma unroll
                for (int c = 0; c < 10; ++c) atomicAdd(pooled + g0 * 10 + c, acc[c]);
            }
        }
    } else if (valid) {
#pragma unroll
        for (int c = 0; c < 10; ++c) atomicAdd(pooled + g * 10 + c, acc[c]);
    }
}

// ---------------- mean + log_softmax --------------------------------------
__global__ void k_final(const float* __restrict__ pooled, const int* __restrict__ gcount,
                        float* __restrict__ out) {
    int g = threadIdx.x;
    if (g >= NG) return;
    float c = fmaxf((float)gcount[g], 1.0f);
    float m[10];
    float mx = -1e30f;
#pragma unroll
    for (int i = 0; i < 10; ++i) {
        m[i] = pooled[g * 10 + i] / c;
        mx = fmaxf(mx, m[i]);
    }
    float s = 0.f;
#pragma unroll
    for (int i = 0; i < 10; ++i) s += expf(m[i] - mx);
    float lse = mx + logf(s);
#pragma unroll
    for (int i = 0; i < 10; ++i) out[g * 10 + i] = m[i] - lse;
}

extern "C" void kernel_launch(void* const* d_in, const int* in_sizes, int n_in,
                              void* d_out, int out_size, void* d_ws, size_t ws_size,
                              hipStream_t stream) {
    const float* x   = (const float*)d_in[0];
    const int*   ei  = (const int*)d_in[1];
    const int*   bat = (const int*)d_in[3];
    const float* W1  = (const float*)d_in[4];
    const float* as1 = (const float*)d_in[5];
    const float* ad1 = (const float*)d_in[6];
    const float* b1  = (const float*)d_in[7];
    const float* W2  = (const float*)d_in[8];
    const float* as2 = (const float*)d_in[9];
    const float* ad2 = (const float*)d_in[10];
    const float* b2  = (const float*)d_in[11];
    float* out = (float*)d_out;

    char* ws = (char*)d_ws;
    size_t off = 0;
    auto alloc = [&](size_t bytes) -> size_t {
        size_t o = off;
        off = (off + bytes + 255) & ~(size_t)255;
        return o;
    };
    size_t o_counts = alloc((size_t)NN * 4);
    size_t o_pooled = alloc((size_t)NG * 10 * 4);
    size_t o_gcount = alloc((size_t)NG * 4);
    size_t zero_bytes = off;
    size_t o_cursor = alloc((size_t)NN * 4);
    size_t o_indptr = alloc((size_t)(NN + 1) * 4);
    size_t o_srcs   = alloc((size_t)ETOT * 4);
    size_t o_ee1    = alloc((size_t)ETOT * 8);
    size_t o_h1f8   = alloc((size_t)NN * 256);
    size_t o_h1o    = alloc((size_t)NN * 256 * 2);
    size_t o_als1   = alloc((size_t)NN * 4 * 4);
    size_t o_ald1   = alloc((size_t)NN * 4 * 4);
    size_t o_h2lin  = alloc((size_t)NN * 10 * 4);
    size_t o_als2   = alloc((size_t)NN * 4);
    size_t o_ald2   = alloc((size_t)NN * 4);
    size_t o_wb     = alloc((size_t)256 * 128 * 2);
    size_t o_xb     = alloc((size_t)NN * 128 * 2);
    (void)ws_size;

    int*   counts = (int*)(ws + o_counts);
    float* pooled = (float*)(ws + o_pooled);
    int*   gcount = (int*)(ws + o_gcount);
    int*   cursor = (int*)(ws + o_cursor);
    int*   indptr = (int*)(ws + o_indptr);
    int*   srcs   = (int*)(ws + o_srcs);
    ushort4* ee1  = (ushort4*)(ws + o_ee1);
    unsigned char*  h1f8 = (unsigned char*)(ws + o_h1f8);
    unsigned short* h1o  = (unsigned short*)(ws + o_h1o);
    float* als1   = (float*)(ws + o_als1);
    float* ald1   = (float*)(ws + o_ald1);
    float* h2lin  = (float*)(ws + o_h2lin);
    float* als2   = (float*)(ws + o_als2);
    float* ald2   = (float*)(ws + o_ald2);
    unsigned short* wb = (unsigned short*)(ws + o_wb);
    unsigned short* xb = (unsigned short*)(ws + o_xb);

    hipMemsetAsync(ws, 0, zero_bytes, stream);

    int gE = (ETOT + 255) / 256;
    int gW = (NN + 3) / 4;
    int gN = (NN + 255) / 256;

    k_hist<<<gE, 256, 0, stream>>>(ei, bat, counts, gcount);
    k_scan<<<1, 1024, 0, stream>>>(counts, indptr, cursor);
    k_cvtw<<<128, 256, 0, stream>>>(W1, wb);
    k_cvtx<<<(NN * 128 / 8 + 255) / 256, 256, 0, stream>>>(x, xb);
    k_gemm1<<<(NN + 31) / 32, 256, 0, stream>>>(xb, wb, as1, ad1, h1f8, als1, ald1);
    k_fill<<<gE, 256, 0, stream>>>(ei, cursor, als1, ald1, srcs, ee1);
    k_gather1<<<gW, 256, 0, stream>>>(indptr, srcs, (const unsigned short*)ee1, h1f8, b1, h1o);
    k_gemm2a<<<gW, 256, 0, stream>>>(h1o, W2, as2, ad2, h2lin, als2, ald2);
    k_g2pool<<<gN, 256, 0, stream>>>(indptr, srcs, als2, ald2, h2lin, b2, bat, pooled);
    k_final<<<1, 64, 0, stream>>>(pooled, gcount, out);
    (void)n_in; (void)in_sizes; (void)out_size;
}

// Round 13
// 237.098 us; speedup vs baseline: 1.0609x; 1.0609x over previous
//
#include <hip/hip_runtime.h>
#include <hip/hip_bf16.h>
#include <math.h>

#define NN 50000
#define EE 500000
#define ETOT (EE + NN)
#define NG 64

typedef __attribute__((ext_vector_type(8))) short short8v;   // 8 bf16 (4 VGPRs)
typedef __attribute__((ext_vector_type(4))) float float4v;   // 4 fp32 acc
typedef __attribute__((ext_vector_type(2))) float float2v;

__device__ __forceinline__ float bf2f(unsigned short u) {
    unsigned int v = ((unsigned int)u) << 16;
    return __builtin_bit_cast(float, v);
}
__device__ __forceinline__ unsigned short f2bf(float f) {
    __hip_bfloat16 h = __float2bfloat16(f);
    return *(unsigned short*)&h;
}
__device__ __forceinline__ unsigned char f2fp8_hw(float f) {
    return (unsigned char)(__builtin_amdgcn_cvt_pk_fp8_f32(f, f, 0, false) & 0xff);
}

// ---------------- histogram of dst + per-graph node counts ----------------
__global__ void k_hist(const int* __restrict__ ei, const int* __restrict__ batch,
                       int* __restrict__ counts, int* __restrict__ gcount) {
    int t = blockIdx.x * 256 + threadIdx.x;
    if (t < ETOT) {
        int dst = (t < EE) ? ei[EE + t] : (t - EE);
        atomicAdd(counts + dst, 1);
    }
    if (t < NN) {
        int g = batch[t];
        int g0 = __shfl(g, 0);
        bool same = (g == g0);
        unsigned long long m = __ballot(same);
        if (same) {
            if ((threadIdx.x & 63) == (__ffsll((long long)m) - 1))
                atomicAdd(gcount + g0, (int)__popcll(m));
        } else {
            atomicAdd(gcount + g, 1);
        }
    }
}

// ---------------- exclusive scan counts -> indptr (+ seed cursor) ---------
__global__ void k_scan(const int* __restrict__ counts, int* __restrict__ indptr,
                       int* __restrict__ cursor) {
    __shared__ int wsum[16];
    __shared__ int carry_s;
    int tid = threadIdx.x;
    int lane = tid & 63;
    int w = tid >> 6;
    if (tid == 0) carry_s = 0;
    __syncthreads();
    for (int base = 0; base < NN; base += 4096) {
        int i = base + tid * 4;
        int v0 = 0, v1 = 0, v2 = 0, v3 = 0;
        if (i + 3 < NN) {
            int4 vv = *(const int4*)&counts[i];
            v0 = vv.x; v1 = vv.y; v2 = vv.z; v3 = vv.w;
        } else {
            if (i < NN) v0 = counts[i];
            if (i + 1 < NN) v1 = counts[i + 1];
            if (i + 2 < NN) v2 = counts[i + 2];
            if (i + 3 < NN) v3 = counts[i + 3];
        }
        int tot = v0 + v1 + v2 + v3;
        int s = tot;
#pragma unroll
        for (int off = 1; off < 64; off <<= 1) {
            int u = __shfl_up(s, off);
            if (lane >= off) s += u;
        }
        if (lane == 63) wsum[w] = s;
        __syncthreads();
        if (w == 0) {
            int t2 = (lane < 16) ? wsum[lane] : 0;
#pragma unroll
            for (int off = 1; off < 16; off <<= 1) {
                int u = __shfl_up(t2, off);
                if (lane >= off) t2 += u;
            }
            if (lane < 16) wsum[lane] = t2;
        }
        __syncthreads();
        int wpre = (w == 0) ? 0 : wsum[w - 1];
        int incl = s + wpre;
        int carry = carry_s;
        int e = carry + incl - tot;
        if (i < NN)     { indptr[i] = e;                cursor[i] = e; }
        if (i + 1 < NN) { int q = e + v0;               indptr[i+1] = q; cursor[i+1] = q; }
        if (i + 2 < NN) { int q = e + v0 + v1;          indptr[i+2] = q; cursor[i+2] = q; }
        if (i + 3 < NN) { int q = e + v0 + v1 + v2;     indptr[i+3] = q; cursor[i+3] = q; }
        __syncthreads();
        if (tid == 1023) carry_s = carry + incl;
        __syncthreads();
    }
    if (tid == 0) indptr[NN] = carry_s;
}

// ---------------- W1 -> bf16 ----------------------------------------------
__global__ void k_cvtw(const float* __restrict__ W1, unsigned short* __restrict__ wb) {
    int t = blockIdx.x * 256 + threadIdx.x;
    if (t >= 256 * 128) return;
    wb[t] = f2bf(W1[t]);
}

// ---------------- x -> bf16, 8 elems/thread -------------------------------
__global__ void k_cvtx(const float* __restrict__ x, unsigned short* __restrict__ xb) {
    int t = blockIdx.x * 256 + threadIdx.x;
    if (t >= NN * 128 / 8) return;
    float4 a = *(const float4*)&x[(size_t)t * 8];
    float4 b = *(const float4*)&x[(size_t)t * 8 + 4];
    float f[8] = {a.x, a.y, a.z, a.w, b.x, b.y, b.z, b.w};
    short8v vh;
#pragma unroll
    for (int j = 0; j < 8; ++j) vh[j] = (short)f2bf(f[j]);
    *(short8v*)&xb[(size_t)t * 8] = vh;
}

// ---------------- GEMM1 via bf16 MFMA + fused alpha logits ----------------
__global__ __launch_bounds__(256) void k_gemm1(const unsigned short* __restrict__ xb,
                                               const unsigned short* __restrict__ wb,
                                               const float* __restrict__ att_s,
                                               const float* __restrict__ att_d,
                                               unsigned char* __restrict__ h1f8,
                                               float* __restrict__ alpha_s,
                                               float* __restrict__ alpha_d) {
    int w = threadIdx.x >> 6;
    int l = threadIdx.x & 63;
    int bm0 = blockIdx.x * 32;
    int i16 = l & 15;
    int kb = (l >> 4) * 8;
    int colb = w * 64;

    short8v a[2][4];
#pragma unroll
    for (int mi = 0; mi < 2; ++mi) {
        int r = bm0 + mi * 16 + i16;
#pragma unroll
        for (int k = 0; k < 4; ++k) {
            if (r < NN) a[mi][k] = *(const short8v*)&xb[(size_t)r * 128 + k * 32 + kb];
            else        a[mi][k] = (short8v){0,0,0,0,0,0,0,0};
        }
    }

    float4v acc[2][4];
#pragma unroll
    for (int mi = 0; mi < 2; ++mi)
#pragma unroll
        for (int ni = 0; ni < 4; ++ni)
            acc[mi][ni] = (float4v){0.f, 0.f, 0.f, 0.f};

#pragma unroll
    for (int k = 0; k < 4; ++k) {
#pragma unroll
        for (int ni = 0; ni < 4; ++ni) {
            short8v b = *(const short8v*)&wb[(size_t)(colb + ni * 16 + i16) * 128 + k * 32 + kb];
            acc[0][ni] = __builtin_amdgcn_mfma_f32_16x16x32_bf16(a[0][k], b, acc[0][ni], 0, 0, 0);
            acc[1][ni] = __builtin_amdgcn_mfma_f32_16x16x32_bf16(a[1][k], b, acc[1][ni], 0, 0, 0);
        }
    }

    // epilogue: fp8 store + fused alpha logits (head = w)
    int drb = (l >> 4) * 4;
    int dc = l & 15;
    float asw[4], adw[4];
#pragma unroll
    for (int ni = 0; ni < 4; ++ni) {
        asw[ni] = att_s[colb + ni * 16 + dc];
        adw[ni] = att_d[colb + ni * 16 + dc];
    }
#pragma unroll
    for (int mi = 0; mi < 2; ++mi) {
#pragma unroll
        for (int r = 0; r < 4; ++r) {
            int row = bm0 + mi * 16 + drb + r;
            float s = 0.f, d = 0.f;
#pragma unroll
            for (int ni = 0; ni < 4; ++ni) {
                float v = acc[mi][ni][r];
                s += v * asw[ni];
                d += v * adw[ni];
                if (row < NN)
                    h1f8[(size_t)row * 256 + colb + ni * 16 + dc] = f2fp8_hw(v);
            }
#pragma unroll
            for (int m = 8; m >= 1; m >>= 1) {
                s += __shfl_xor(s, m);
                d += __shfl_xor(d, m);
            }
            if (dc == 0 && row < NN) {
                alpha_s[row * 4 + w] = s;
                alpha_d[row * 4 + w] = d;
            }
        }
    }
}

// ---------------- bucket fill + edge softmax weights (bf16 x4) + dsts -----
__global__ void k_fill(const int* __restrict__ ei, int* __restrict__ cursor,
                       const float* __restrict__ als, const float* __restrict__ ald,
                       int* __restrict__ srcs, int* __restrict__ dsts,
                       ushort4* __restrict__ ee1) {
    int t = blockIdx.x * 256 + threadIdx.x;
    if (t >= ETOT) return;
    int src = (t < EE) ? ei[t] : (t - EE);
    int dst = (t < EE) ? ei[EE + t] : (t - EE);
    int p = atomicAdd(cursor + dst, 1);
    srcs[p] = src;
    dsts[p] = dst;
    float4 as = *(const float4*)&als[src * 4];
    float4 ad = *(const float4*)&ald[dst * 4];
    float e0 = as.x + ad.x, e1 = as.y + ad.y, e2 = as.z + ad.z, e3 = as.w + ad.w;
    e0 = e0 > 0.f ? e0 : 0.2f * e0;
    e1 = e1 > 0.f ? e1 : 0.2f * e1;
    e2 = e2 > 0.f ? e2 : 0.2f * e2;
    e3 = e3 > 0.f ? e3 : 0.2f * e3;
    ushort4 ev;
    ev.x = f2bf(__expf(e0));
    ev.y = f2bf(__expf(e1));
    ev.z = f2bf(__expf(e2));
    ev.w = f2bf(__expf(e3));
    ee1[p] = ev;
}

// ---------------- gather-aggregate layer 1 (4-edge unroll) ----------------
__global__ void k_gather1(const int* __restrict__ indptr, const int* __restrict__ srcs,
                          const unsigned short* __restrict__ ee1,
                          const unsigned char* __restrict__ h1f8, const float* __restrict__ b1,
                          unsigned short* __restrict__ h1o) {
    int wid = (blockIdx.x * 256 + threadIdx.x) >> 6;
    int l = threadIdx.x & 63;
    if (wid >= NN) return;
    int p0 = __builtin_amdgcn_readfirstlane(indptr[wid]);
    int p1 = __builtin_amdgcn_readfirstlane(indptr[wid + 1]);
    int head = l >> 4;
    float acc0 = 0.f, acc1 = 0.f, acc2 = 0.f, acc3 = 0.f, dsum = 0.f;
    int p = p0;
    for (; p + 3 < p1; p += 4) {
        int s0 = srcs[p], s1 = srcs[p + 1], s2 = srcs[p + 2], s3 = srcs[p + 3];
        float w0 = bf2f(ee1[(p + 0) * 4 + head]);
        float w1 = bf2f(ee1[(p + 1) * 4 + head]);
        float w2 = bf2f(ee1[(p + 2) * 4 + head]);
        float w3 = bf2f(ee1[(p + 3) * 4 + head]);
        unsigned int hv0 = *(const unsigned int*)&h1f8[(size_t)s0 * 256 + l * 4];
        unsigned int hv1 = *(const unsigned int*)&h1f8[(size_t)s1 * 256 + l * 4];
        unsigned int hv2 = *(const unsigned int*)&h1f8[(size_t)s2 * 256 + l * 4];
        unsigned int hv3 = *(const unsigned int*)&h1f8[(size_t)s3 * 256 + l * 4];
        dsum += (w0 + w1) + (w2 + w3);
        float2v lo, hi;
        lo = __builtin_amdgcn_cvt_pk_f32_fp8(hv0, false);
        hi = __builtin_amdgcn_cvt_pk_f32_fp8(hv0, true);
        acc0 += w0 * lo.x; acc1 += w0 * lo.y; acc2 += w0 * hi.x; acc3 += w0 * hi.y;
        lo = __builtin_amdgcn_cvt_pk_f32_fp8(hv1, false);
        hi = __builtin_amdgcn_cvt_pk_f32_fp8(hv1, true);
        acc0 += w1 * lo.x; acc1 += w1 * lo.y; acc2 += w1 * hi.x; acc3 += w1 * hi.y;
        lo = __builtin_amdgcn_cvt_pk_f32_fp8(hv2, false);
        hi = __builtin_amdgcn_cvt_pk_f32_fp8(hv2, true);
        acc0 += w2 * lo.x; acc1 += w2 * lo.y; acc2 += w2 * hi.x; acc3 += w2 * hi.y;
        lo = __builtin_amdgcn_cvt_pk_f32_fp8(hv3, false);
        hi = __builtin_amdgcn_cvt_pk_f32_fp8(hv3, true);
        acc0 += w3 * lo.x; acc1 += w3 * lo.y; acc2 += w3 * hi.x; acc3 += w3 * hi.y;
    }
    for (; p < p1; ++p) {
        int s = srcs[p];
        float w = bf2f(ee1[p * 4 + head]);
        unsigned int hv = *(const unsigned int*)&h1f8[(size_t)s * 256 + l * 4];
        float2v lo = __builtin_amdgcn_cvt_pk_f32_fp8(hv, false);
        float2v hi = __builtin_amdgcn_cvt_pk_f32_fp8(hv, true);
        dsum += w;
        acc0 += w * lo.x;
        acc1 += w * lo.y;
        acc2 += w * hi.x;
        acc3 += w * hi.y;
    }
    float inv = 1.0f / dsum;
    float4 bv = *(const float4*)&b1[l * 4];
    float o0 = acc0 * inv + bv.x;
    float o1 = acc1 * inv + bv.y;
    float o2 = acc2 * inv + bv.z;
    float o3 = acc3 * inv + bv.w;
    o0 = o0 > 0.f ? o0 : expm1f(o0);
    o1 = o1 > 0.f ? o1 : expm1f(o1);
    o2 = o2 > 0.f ? o2 : expm1f(o2);
    o3 = o3 > 0.f ? o3 : expm1f(o3);
    ushort4 ov;
    ov.x = f2bf(o0); ov.y = f2bf(o1); ov.z = f2bf(o2); ov.w = f2bf(o3);
    *(ushort4*)&h1o[(size_t)wid * 256 + l * 4] = ov;
}

// ---------------- GEMM2 (wave/node) + attention logits layer 2 ------------
// h2lin padded to stride 16 (one aligned 64B line per node).
__global__ void k_gemm2a(const unsigned short* __restrict__ h1o, const float* __restrict__ W2,
                         const float* __restrict__ as2v, const float* __restrict__ ad2v,
                         float* __restrict__ h2lin, float* __restrict__ alpha_s2,
                         float* __restrict__ alpha_d2) {
    int wid = (blockIdx.x * 256 + threadIdx.x) >> 6;
    int l = threadIdx.x & 63;
    if (wid >= NN) return;
    ushort4 hv = *(const ushort4*)&h1o[(size_t)wid * 256 + l * 4];
    float h0 = bf2f(hv.x), h1_ = bf2f(hv.y), h2 = bf2f(hv.z), h3 = bf2f(hv.w);
    float t[10];
#pragma unroll
    for (int o = 0; o < 10; ++o) {
        float4 wv = *(const float4*)&W2[o * 256 + l * 4];
        t[o] = h0 * wv.x + h1_ * wv.y + h2 * wv.z + h3 * wv.w;
    }
#pragma unroll
    for (int m = 32; m > 0; m >>= 1) {
#pragma unroll
        for (int o = 0; o < 10; ++o) t[o] += __shfl_xor(t[o], m);
    }
    if (l == 0) {
        float as = 0.f, ad = 0.f;
#pragma unroll
        for (int o = 0; o < 10; ++o) {
            h2lin[(size_t)wid * 16 + o] = t[o];
            as += t[o] * as2v[o];
            ad += t[o] * ad2v[o];
        }
        alpha_s2[wid] = as;
        alpha_d2[wid] = ad;
    }
}

// ---------------- edge weights layer 2 (edge-parallel) --------------------
__global__ void k_ee2(const int* __restrict__ srcs, const int* __restrict__ dsts,
                      const float* __restrict__ als2, const float* __restrict__ ald2,
                      float* __restrict__ ee2) {
    int p = blockIdx.x * 256 + threadIdx.x;
    if (p >= ETOT) return;
    float v = als2[srcs[p]] + ald2[dsts[p]];
    v = v > 0.f ? v : 0.2f * v;
    ee2[p] = __expf(v);
}

// ---------------- gather layer 2 + softmax + bias + fused mean-pool -------
// 16-lane group per node (4 nodes/wave); lane c<10 owns channel c.
__global__ void k_g2pool(const int* __restrict__ indptr, const int* __restrict__ srcs,
                         const float* __restrict__ ee2, const float* __restrict__ h2lin,
                         const float* __restrict__ b2, const int* __restrict__ batch,
                         float* __restrict__ pooled) {
    int wave = (blockIdx.x * 256 + threadIdx.x) >> 6;
    int lane = threadIdx.x & 63;
    int grp = lane >> 4, c = lane & 15;
    int node = wave * 4 + grp;
    float acc = 0.f;
    int g = -1;
    if (node < NN) {
        int p0 = indptr[node], p1 = indptr[node + 1];
        float dsum = 0.f;
        for (int p = p0; p < p1; ++p) {
            float w = ee2[p];
            dsum += w;
            if (c < 10) acc += w * h2lin[(size_t)srcs[p] * 16 + c];
        }
        acc = (c < 10) ? (acc / dsum + b2[c < 10 ? c : 0]) : 0.f;
        g = batch[node];
    }
    // pooling: wave-uniform graph fast path
    int g0 = __shfl(g, 0);
    bool uni = __all((node >= NN) || (g == g0));
    if (uni) {
        if (g0 >= 0) {
            acc += __shfl_xor(acc, 16);
            acc += __shfl_xor(acc, 32);
            if (grp == 0 && c < 10)
                atomicAdd(pooled + g0 * 10 + c, acc);
        }
    } else if (node < NN && c < 10) {
        atomicAdd(pooled + g * 10 + c, acc);
    }
}

// ---------------- mean + log_softmax --------------------------------------
__global__ void k_final(const float* __restrict__ pooled, const int* __restrict__ gcount,
                        float* __restrict__ out) {
    int g = threadIdx.x;
    if (g >= NG) return;
    float c = fmaxf((float)gcount[g], 1.0f);
    float m[10];
    float mx = -1e30f;
#pragma unroll
    for (int i = 0; i < 10; ++i) {
        m[i] = pooled[g * 10 + i] / c;
        mx = fmaxf(mx, m[i]);
    }
    float s = 0.f;
#pragma unroll
    for (int i = 0; i < 10; ++i) s += expf(m[i] - mx);
    float lse = mx + logf(s);
#pragma unroll
    for (int i = 0; i < 10; ++i) out[g * 10 + i] = m[i] - lse;
}

extern "C" void kernel_launch(void* const* d_in, const int* in_sizes, int n_in,
                              void* d_out, int out_size, void* d_ws, size_t ws_size,
                              hipStream_t stream) {
    const float* x   = (const float*)d_in[0];
    const int*   ei  = (const int*)d_in[1];
    const int*   bat = (const int*)d_in[3];
    const float* W1  = (const float*)d_in[4];
    const float* as1 = (const float*)d_in[5];
    const float* ad1 = (const float*)d_in[6];
    const float* b1  = (const float*)d_in[7];
    const float* W2  = (const float*)d_in[8];
    const float* as2 = (const float*)d_in[9];
    const float* ad2 = (const float*)d_in[10];
    const float* b2  = (const float*)d_in[11];
    float* out = (float*)d_out;

    char* ws = (char*)d_ws;
    size_t off = 0;
    auto alloc = [&](size_t bytes) -> size_t {
        size_t o = off;
        off = (off + bytes + 255) & ~(size_t)255;
        return o;
    };
    size_t o_counts = alloc((size_t)NN * 4);
    size_t o_pooled = alloc((size_t)NG * 10 * 4);
    size_t o_gcount = alloc((size_t)NG * 4);
    size_t zero_bytes = off;
    size_t o_cursor = alloc((size_t)NN * 4);
    size_t o_indptr = alloc((size_t)(NN + 1) * 4);
    size_t o_srcs   = alloc((size_t)ETOT * 4);
    size_t o_dsts   = alloc((size_t)ETOT * 4);
    size_t o_ee1    = alloc((size_t)ETOT * 8);
    size_t o_ee2    = alloc((size_t)ETOT * 4);
    size_t o_h1f8   = alloc((size_t)NN * 256);
    size_t o_h1o    = alloc((size_t)NN * 256 * 2);
    size_t o_als1   = alloc((size_t)NN * 4 * 4);
    size_t o_ald1   = alloc((size_t)NN * 4 * 4);
    size_t o_h2lin  = alloc((size_t)NN * 16 * 4);
    size_t o_als2   = alloc((size_t)NN * 4);
    size_t o_ald2   = alloc((size_t)NN * 4);
    size_t o_wb     = alloc((size_t)256 * 128 * 2);
    size_t o_xb     = alloc((size_t)NN * 128 * 2);
    (void)ws_size;

    int*   counts = (int*)(ws + o_counts);
    float* pooled = (float*)(ws + o_pooled);
    int*   gcount = (int*)(ws + o_gcount);
    int*   cursor = (int*)(ws + o_cursor);
    int*   indptr = (int*)(ws + o_indptr);
    int*   srcs   = (int*)(ws + o_srcs);
    int*   dsts   = (int*)(ws + o_dsts);
    ushort4* ee1  = (ushort4*)(ws + o_ee1);
    float* ee2    = (float*)(ws + o_ee2);
    unsigned char*  h1f8 = (unsigned char*)(ws + o_h1f8);
    unsigned short* h1o  = (unsigned short*)(ws + o_h1o);
    float* als1   = (float*)(ws + o_als1);
    float* ald1   = (float*)(ws + o_ald1);
    float* h2lin  = (float*)(ws + o_h2lin);
    float* als2   = (float*)(ws + o_als2);
    float* ald2   = (float*)(ws + o_ald2);
    unsigned short* wb = (unsigned short*)(ws + o_wb);
    unsigned short* xb = (unsigned short*)(ws + o_xb);

    hipMemsetAsync(ws, 0, zero_bytes, stream);

    int gE = (ETOT + 255) / 256;
    int gW = (NN + 3) / 4;

    k_hist<<<gE, 256, 0, stream>>>(ei, bat, counts, gcount);
    k_scan<<<1, 1024, 0, stream>>>(counts, indptr, cursor);
    k_cvtw<<<128, 256, 0, stream>>>(W1, wb);
    k_cvtx<<<(NN * 128 / 8 + 255) / 256, 256, 0, stream>>>(x, xb);
    k_gemm1<<<(NN + 31) / 32, 256, 0, stream>>>(xb, wb, as1, ad1, h1f8, als1, ald1);
    k_fill<<<gE, 256, 0, stream>>>(ei, cursor, als1, ald1, srcs, dsts, ee1);
    k_gather1<<<gW, 256, 0, stream>>>(indptr, srcs, (const unsigned short*)ee1, h1f8, b1, h1o);
    k_gemm2a<<<gW, 256, 0, stream>>>(h1o, W2, as2, ad2, h2lin, als2, ald2);
    k_ee2<<<gE, 256, 0, stream>>>(srcs, dsts, als2, ald2, ee2);
    k_g2pool<<<gW, 256, 0, stream>>>(indptr, srcs, ee2, h2lin, b2, bat, pooled);
    k_final<<<1, 64, 0, stream>>>(pooled, gcount, out);
    (void)n_in; (void)in_sizes; (void)out_size;
}

// Round 14
// 235.933 us; speedup vs baseline: 1.0661x; 1.0049x over previous
//
#include <hip/hip_runtime.h>
#include <hip/hip_bf16.h>
#include <math.h>

#define NN 50000
#define EE 500000
#define ETOT (EE + NN)
#define NG 64

typedef __attribute__((ext_vector_type(8))) short short8v;   // 8 bf16 (4 VGPRs)
typedef __attribute__((ext_vector_type(4))) float float4v;   // 4 fp32 acc
typedef __attribute__((ext_vector_type(2))) float float2v;

__device__ __forceinline__ float bf2f(unsigned short u) {
    unsigned int v = ((unsigned int)u) << 16;
    return __builtin_bit_cast(float, v);
}
__device__ __forceinline__ unsigned short f2bf(float f) {
    __hip_bfloat16 h = __float2bfloat16(f);
    return *(unsigned short*)&h;
}
__device__ __forceinline__ unsigned char f2fp8_hw(float f) {
    return (unsigned char)(__builtin_amdgcn_cvt_pk_fp8_f32(f, f, 0, false) & 0xff);
}

// ---------------- zero the small scratch region (replaces slow rocclr fill)
__global__ void k_zero(uint4* __restrict__ p, int n16) {
    int t = blockIdx.x * 256 + threadIdx.x;
    if (t < n16) p[t] = make_uint4(0, 0, 0, 0);
}

// ---------------- histogram of dst + per-graph node counts ----------------
__global__ void k_hist(const int* __restrict__ ei, const int* __restrict__ batch,
                       int* __restrict__ counts, int* __restrict__ gcount) {
    int t = blockIdx.x * 256 + threadIdx.x;
    if (t < ETOT) {
        int dst = (t < EE) ? ei[EE + t] : (t - EE);
        atomicAdd(counts + dst, 1);
    }
    if (t < NN) {
        int g = batch[t];
        int g0 = __shfl(g, 0);
        bool same = (g == g0);
        unsigned long long m = __ballot(same);
        if (same) {
            if ((threadIdx.x & 63) == (__ffsll((long long)m) - 1))
                atomicAdd(gcount + g0, (int)__popcll(m));
        } else {
            atomicAdd(gcount + g, 1);
        }
    }
}

// ---------------- exclusive scan counts -> indptr (+ seed cursor) ---------
__global__ void k_scan(const int* __restrict__ counts, int* __restrict__ indptr,
                       int* __restrict__ cursor) {
    __shared__ int wsum[16];
    __shared__ int carry_s;
    int tid = threadIdx.x;
    int lane = tid & 63;
    int w = tid >> 6;
    if (tid == 0) carry_s = 0;
    __syncthreads();
    for (int base = 0; base < NN; base += 4096) {
        int i = base + tid * 4;
        int v0 = 0, v1 = 0, v2 = 0, v3 = 0;
        if (i + 3 < NN) {
            int4 vv = *(const int4*)&counts[i];
            v0 = vv.x; v1 = vv.y; v2 = vv.z; v3 = vv.w;
        } else {
            if (i < NN) v0 = counts[i];
            if (i + 1 < NN) v1 = counts[i + 1];
            if (i + 2 < NN) v2 = counts[i + 2];
            if (i + 3 < NN) v3 = counts[i + 3];
        }
        int tot = v0 + v1 + v2 + v3;
        int s = tot;
#pragma unroll
        for (int off = 1; off < 64; off <<= 1) {
            int u = __shfl_up(s, off);
            if (lane >= off) s += u;
        }
        if (lane == 63) wsum[w] = s;
        __syncthreads();
        if (w == 0) {
            int t2 = (lane < 16) ? wsum[lane] : 0;
#pragma unroll
            for (int off = 1; off < 16; off <<= 1) {
                int u = __shfl_up(t2, off);
                if (lane >= off) t2 += u;
            }
            if (lane < 16) wsum[lane] = t2;
        }
        __syncthreads();
        int wpre = (w == 0) ? 0 : wsum[w - 1];
        int incl = s + wpre;
        int carry = carry_s;
        int e = carry + incl - tot;
        if (i < NN)     { indptr[i] = e;                cursor[i] = e; }
        if (i + 1 < NN) { int q = e + v0;               indptr[i+1] = q; cursor[i+1] = q; }
        if (i + 2 < NN) { int q = e + v0 + v1;          indptr[i+2] = q; cursor[i+2] = q; }
        if (i + 3 < NN) { int q = e + v0 + v1 + v2;     indptr[i+3] = q; cursor[i+3] = q; }
        __syncthreads();
        if (tid == 1023) carry_s = carry + incl;
        __syncthreads();
    }
    if (tid == 0) indptr[NN] = carry_s;
}

// ---------------- W1 -> bf16 ----------------------------------------------
__global__ void k_cvtw(const float* __restrict__ W1, unsigned short* __restrict__ wb) {
    int t = blockIdx.x * 256 + threadIdx.x;
    if (t >= 256 * 128) return;
    wb[t] = f2bf(W1[t]);
}

// ---------------- x -> bf16, 8 elems/thread -------------------------------
__global__ void k_cvtx(const float* __restrict__ x, unsigned short* __restrict__ xb) {
    int t = blockIdx.x * 256 + threadIdx.x;
    if (t >= NN * 128 / 8) return;
    float4 a = *(const float4*)&x[(size_t)t * 8];
    float4 b = *(const float4*)&x[(size_t)t * 8 + 4];
    float f[8] = {a.x, a.y, a.z, a.w, b.x, b.y, b.z, b.w};
    short8v vh;
#pragma unroll
    for (int j = 0; j < 8; ++j) vh[j] = (short)f2bf(f[j]);
    *(short8v*)&xb[(size_t)t * 8] = vh;
}

// ---------------- GEMM1 via bf16 MFMA + fused alpha logits ----------------
__global__ __launch_bounds__(256) void k_gemm1(const unsigned short* __restrict__ xb,
                                               const unsigned short* __restrict__ wb,
                                               const float* __restrict__ att_s,
                                               const float* __restrict__ att_d,
                                               unsigned char* __restrict__ h1f8,
                                               float* __restrict__ alpha_s,
                                               float* __restrict__ alpha_d) {
    int w = threadIdx.x >> 6;
    int l = threadIdx.x & 63;
    int bm0 = blockIdx.x * 32;
    int i16 = l & 15;
    int kb = (l >> 4) * 8;
    int colb = w * 64;

    short8v a[2][4];
#pragma unroll
    for (int mi = 0; mi < 2; ++mi) {
        int r = bm0 + mi * 16 + i16;
#pragma unroll
        for (int k = 0; k < 4; ++k) {
            if (r < NN) a[mi][k] = *(const short8v*)&xb[(size_t)r * 128 + k * 32 + kb];
            else        a[mi][k] = (short8v){0,0,0,0,0,0,0,0};
        }
    }

    float4v acc[2][4];
#pragma unroll
    for (int mi = 0; mi < 2; ++mi)
#pragma unroll
        for (int ni = 0; ni < 4; ++ni)
            acc[mi][ni] = (float4v){0.f, 0.f, 0.f, 0.f};

#pragma unroll
    for (int k = 0; k < 4; ++k) {
#pragma unroll
        for (int ni = 0; ni < 4; ++ni) {
            short8v b = *(const short8v*)&wb[(size_t)(colb + ni * 16 + i16) * 128 + k * 32 + kb];
            acc[0][ni] = __builtin_amdgcn_mfma_f32_16x16x32_bf16(a[0][k], b, acc[0][ni], 0, 0, 0);
            acc[1][ni] = __builtin_amdgcn_mfma_f32_16x16x32_bf16(a[1][k], b, acc[1][ni], 0, 0, 0);
        }
    }

    // epilogue: fp8 store + fused alpha logits (head = w)
    int drb = (l >> 4) * 4;
    int dc = l & 15;
    float asw[4], adw[4];
#pragma unroll
    for (int ni = 0; ni < 4; ++ni) {
        asw[ni] = att_s[colb + ni * 16 + dc];
        adw[ni] = att_d[colb + ni * 16 + dc];
    }
#pragma unroll
    for (int mi = 0; mi < 2; ++mi) {
#pragma unroll
        for (int r = 0; r < 4; ++r) {
            int row = bm0 + mi * 16 + drb + r;
            float s = 0.f, d = 0.f;
#pragma unroll
            for (int ni = 0; ni < 4; ++ni) {
                float v = acc[mi][ni][r];
                s += v * asw[ni];
                d += v * adw[ni];
                if (row < NN)
                    h1f8[(size_t)row * 256 + colb + ni * 16 + dc] = f2fp8_hw(v);
            }
#pragma unroll
            for (int m = 8; m >= 1; m >>= 1) {
                s += __shfl_xor(s, m);
                d += __shfl_xor(d, m);
            }
            if (dc == 0 && row < NN) {
                alpha_s[row * 4 + w] = s;
                alpha_d[row * 4 + w] = d;
            }
        }
    }
}

// ---------------- bucket fill + edge softmax weights (bf16 x4) + dsts -----
__global__ void k_fill(const int* __restrict__ ei, int* __restrict__ cursor,
                       const float* __restrict__ als, const float* __restrict__ ald,
                       int* __restrict__ srcs, int* __restrict__ dsts,
                       ushort4* __restrict__ ee1) {
    int t = blockIdx.x * 256 + threadIdx.x;
    if (t >= ETOT) return;
    int src = (t < EE) ? ei[t] : (t - EE);
    int dst = (t < EE) ? ei[EE + t] : (t - EE);
    int p = atomicAdd(cursor + dst, 1);
    srcs[p] = src;
    dsts[p] = dst;
    float4 as = *(const float4*)&als[src * 4];
    float4 ad = *(const float4*)&ald[dst * 4];
    float e0 = as.x + ad.x, e1 = as.y + ad.y, e2 = as.z + ad.z, e3 = as.w + ad.w;
    e0 = e0 > 0.f ? e0 : 0.2f * e0;
    e1 = e1 > 0.f ? e1 : 0.2f * e1;
    e2 = e2 > 0.f ? e2 : 0.2f * e2;
    e3 = e3 > 0.f ? e3 : 0.2f * e3;
    ushort4 ev;
    ev.x = f2bf(__expf(e0));
    ev.y = f2bf(__expf(e1));
    ev.z = f2bf(__expf(e2));
    ev.w = f2bf(__expf(e3));
    ee1[p] = ev;
}

// ---------------- gather-aggregate layer 1 (4-edge unroll) ----------------
__global__ void k_gather1(const int* __restrict__ indptr, const int* __restrict__ srcs,
                          const unsigned short* __restrict__ ee1,
                          const unsigned char* __restrict__ h1f8, const float* __restrict__ b1,
                          unsigned short* __restrict__ h1o) {
    int wid = (blockIdx.x * 256 + threadIdx.x) >> 6;
    int l = threadIdx.x & 63;
    if (wid >= NN) return;
    int p0 = __builtin_amdgcn_readfirstlane(indptr[wid]);
    int p1 = __builtin_amdgcn_readfirstlane(indptr[wid + 1]);
    int head = l >> 4;
    float acc0 = 0.f, acc1 = 0.f, acc2 = 0.f, acc3 = 0.f, dsum = 0.f;
    int p = p0;
    for (; p + 3 < p1; p += 4) {
        int s0 = srcs[p], s1 = srcs[p + 1], s2 = srcs[p + 2], s3 = srcs[p + 3];
        float w0 = bf2f(ee1[(p + 0) * 4 + head]);
        float w1 = bf2f(ee1[(p + 1) * 4 + head]);
        float w2 = bf2f(ee1[(p + 2) * 4 + head]);
        float w3 = bf2f(ee1[(p + 3) * 4 + head]);
        unsigned int hv0 = *(const unsigned int*)&h1f8[(size_t)s0 * 256 + l * 4];
        unsigned int hv1 = *(const unsigned int*)&h1f8[(size_t)s1 * 256 + l * 4];
        unsigned int hv2 = *(const unsigned int*)&h1f8[(size_t)s2 * 256 + l * 4];
        unsigned int hv3 = *(const unsigned int*)&h1f8[(size_t)s3 * 256 + l * 4];
        dsum += (w0 + w1) + (w2 + w3);
        float2v lo, hi;
        lo = __builtin_amdgcn_cvt_pk_f32_fp8(hv0, false);
        hi = __builtin_amdgcn_cvt_pk_f32_fp8(hv0, true);
        acc0 += w0 * lo.x; acc1 += w0 * lo.y; acc2 += w0 * hi.x; acc3 += w0 * hi.y;
        lo = __builtin_amdgcn_cvt_pk_f32_fp8(hv1, false);
        hi = __builtin_amdgcn_cvt_pk_f32_fp8(hv1, true);
        acc0 += w1 * lo.x; acc1 += w1 * lo.y; acc2 += w1 * hi.x; acc3 += w1 * hi.y;
        lo = __builtin_amdgcn_cvt_pk_f32_fp8(hv2, false);
        hi = __builtin_amdgcn_cvt_pk_f32_fp8(hv2, true);
        acc0 += w2 * lo.x; acc1 += w2 * lo.y; acc2 += w2 * hi.x; acc3 += w2 * hi.y;
        lo = __builtin_amdgcn_cvt_pk_f32_fp8(hv3, false);
        hi = __builtin_amdgcn_cvt_pk_f32_fp8(hv3, true);
        acc0 += w3 * lo.x; acc1 += w3 * lo.y; acc2 += w3 * hi.x; acc3 += w3 * hi.y;
    }
    for (; p < p1; ++p) {
        int s = srcs[p];
        float w = bf2f(ee1[p * 4 + head]);
        unsigned int hv = *(const unsigned int*)&h1f8[(size_t)s * 256 + l * 4];
        float2v lo = __builtin_amdgcn_cvt_pk_f32_fp8(hv, false);
        float2v hi = __builtin_amdgcn_cvt_pk_f32_fp8(hv, true);
        dsum += w;
        acc0 += w * lo.x;
        acc1 += w * lo.y;
        acc2 += w * hi.x;
        acc3 += w * hi.y;
    }
    float inv = 1.0f / dsum;
    float4 bv = *(const float4*)&b1[l * 4];
    float o0 = acc0 * inv + bv.x;
    float o1 = acc1 * inv + bv.y;
    float o2 = acc2 * inv + bv.z;
    float o3 = acc3 * inv + bv.w;
    o0 = o0 > 0.f ? o0 : expm1f(o0);
    o1 = o1 > 0.f ? o1 : expm1f(o1);
    o2 = o2 > 0.f ? o2 : expm1f(o2);
    o3 = o3 > 0.f ? o3 : expm1f(o3);
    ushort4 ov;
    ov.x = f2bf(o0); ov.y = f2bf(o1); ov.z = f2bf(o2); ov.w = f2bf(o3);
    *(ushort4*)&h1o[(size_t)wid * 256 + l * 4] = ov;
}

// ---------------- GEMM2 (wave/node) + attention logits layer 2 ------------
__global__ void k_gemm2a(const unsigned short* __restrict__ h1o, const float* __restrict__ W2,
                         const float* __restrict__ as2v, const float* __restrict__ ad2v,
                         float* __restrict__ h2lin, float* __restrict__ alpha_s2,
                         float* __restrict__ alpha_d2) {
    int wid = (blockIdx.x * 256 + threadIdx.x) >> 6;
    int l = threadIdx.x & 63;
    if (wid >= NN) return;
    ushort4 hv = *(const ushort4*)&h1o[(size_t)wid * 256 + l * 4];
    float h0 = bf2f(hv.x), h1_ = bf2f(hv.y), h2 = bf2f(hv.z), h3 = bf2f(hv.w);
    float t[10];
#pragma unroll
    for (int o = 0; o < 10; ++o) {
        float4 wv = *(const float4*)&W2[o * 256 + l * 4];
        t[o] = h0 * wv.x + h1_ * wv.y + h2 * wv.z + h3 * wv.w;
    }
#pragma unroll
    for (int m = 32; m > 0; m >>= 1) {
#pragma unroll
        for (int o = 0; o < 10; ++o) t[o] += __shfl_xor(t[o], m);
    }
    if (l == 0) {
        float as = 0.f, ad = 0.f;
#pragma unroll
        for (int o = 0; o < 10; ++o) {
            h2lin[(size_t)wid * 16 + o] = t[o];
            as += t[o] * as2v[o];
            ad += t[o] * ad2v[o];
        }
        alpha_s2[wid] = as;
        alpha_d2[wid] = ad;
    }
}

// ---------------- edge weights layer 2 (edge-parallel) --------------------
__global__ void k_ee2(const int* __restrict__ srcs, const int* __restrict__ dsts,
                      const float* __restrict__ als2, const float* __restrict__ ald2,
                      float* __restrict__ ee2) {
    int p = blockIdx.x * 256 + threadIdx.x;
    if (p >= ETOT) return;
    float v = als2[srcs[p]] + ald2[dsts[p]];
    v = v > 0.f ? v : 0.2f * v;
    ee2[p] = __expf(v);
}

// ---------------- gather layer 2 + softmax + bias + fused mean-pool -------
__global__ void k_g2pool(const int* __restrict__ indptr, const int* __restrict__ srcs,
                         const float* __restrict__ ee2, const float* __restrict__ h2lin,
                         const float* __restrict__ b2, const int* __restrict__ batch,
                         float* __restrict__ pooled) {
    int wave = (blockIdx.x * 256 + threadIdx.x) >> 6;
    int lane = threadIdx.x & 63;
    int grp = lane >> 4, c = lane & 15;
    int node = wave * 4 + grp;
    float acc = 0.f;
    int g = -1;
    if (node < NN) {
        int p0 = indptr[node], p1 = indptr[node + 1];
        float dsum = 0.f;
        for (int p = p0; p < p1; ++p) {
            float w = ee2[p];
            dsum += w;
            if (c < 10) acc += w * h2lin[(size_t)srcs[p] * 16 + c];
        }
        acc = (c < 10) ? (acc / dsum + b2[c < 10 ? c : 0]) : 0.f;
        g = batch[node];
    }
    int g0 = __shfl(g, 0);
    bool uni = __all((node >= NN) || (g == g0));
    if (uni) {
        if (g0 >= 0) {
            acc += __shfl_xor(acc, 16);
            acc += __shfl_xor(acc, 32);
            if (grp == 0 && c < 10)
                atomicAdd(pooled + g0 * 10 + c, acc);
        }
    } else if (node < NN && c < 10) {
        atomicAdd(pooled + g * 10 + c, acc);
    }
}

// ---------------- mean + log_softmax --------------------------------------
__global__ void k_final(const float* __restrict__ pooled, const int* __restrict__ gcount,
                        float* __restrict__ out) {
    int g = threadIdx.x;
    if (g >= NG) return;
    float c = fmaxf((float)gcount[g], 1.0f);
    float m[10];
    float mx = -1e30f;
#pragma unroll
    for (int i = 0; i < 10; ++i) {
        m[i] = pooled[g * 10 + i] / c;
        mx = fmaxf(mx, m[i]);
    }
    float s = 0.f;
#pragma unroll
    for (int i = 0; i < 10; ++i) s += expf(m[i] - mx);
    float lse = mx + logf(s);
#pragma unroll
    for (int i = 0; i < 10; ++i) out[g * 10 + i] = m[i] - lse;
}

extern "C" void kernel_launch(void* const* d_in, const int* in_sizes, int n_in,
                              void* d_out, int out_size, void* d_ws, size_t ws_size,
                              hipStream_t stream) {
    const float* x   = (const float*)d_in[0];
    const int*   ei  = (const int*)d_in[1];
    const int*   bat = (const int*)d_in[3];
    const float* W1  = (const float*)d_in[4];
    const float* as1 = (const float*)d_in[5];
    const float* ad1 = (const float*)d_in[6];
    const float* b1  = (const float*)d_in[7];
    const float* W2  = (const float*)d_in[8];
    const float* as2 = (const float*)d_in[9];
    const float* ad2 = (const float*)d_in[10];
    const float* b2  = (const float*)d_in[11];
    float* out = (float*)d_out;

    char* ws = (char*)d_ws;
    size_t off = 0;
    auto alloc = [&](size_t bytes) -> size_t {
        size_t o = off;
        off = (off + bytes + 255) & ~(size_t)255;
        return o;
    };
    size_t o_counts = alloc((size_t)NN * 4);
    size_t o_pooled = alloc((size_t)NG * 10 * 4);
    size_t o_gcount = alloc((size_t)NG * 4);
    size_t zero_bytes = off;
    size_t o_cursor = alloc((size_t)NN * 4);
    size_t o_indptr = alloc((size_t)(NN + 1) * 4);
    size_t o_srcs   = alloc((size_t)ETOT * 4);
    size_t o_dsts   = alloc((size_t)ETOT * 4);
    size_t o_ee1    = alloc((size_t)ETOT * 8);
    size_t o_ee2    = alloc((size_t)ETOT * 4);
    size_t o_h1f8   = alloc((size_t)NN * 256);
    size_t o_h1o    = alloc((size_t)NN * 256 * 2);
    size_t o_als1   = alloc((size_t)NN * 4 * 4);
    size_t o_ald1   = alloc((size_t)NN * 4 * 4);
    size_t o_h2lin  = alloc((size_t)NN * 16 * 4);
    size_t o_als2   = alloc((size_t)NN * 4);
    size_t o_ald2   = alloc((size_t)NN * 4);
    size_t o_wb     = alloc((size_t)256 * 128 * 2);
    size_t o_xb     = alloc((size_t)NN * 128 * 2);
    (void)ws_size;

    int*   counts = (int*)(ws + o_counts);
    float* pooled = (float*)(ws + o_pooled);
    int*   gcount = (int*)(ws + o_gcount);
    int*   cursor = (int*)(ws + o_cursor);
    int*   indptr = (int*)(ws + o_indptr);
    int*   srcs   = (int*)(ws + o_srcs);
    int*   dsts   = (int*)(ws + o_dsts);
    ushort4* ee1  = (ushort4*)(ws + o_ee1);
    float* ee2    = (float*)(ws + o_ee2);
    unsigned char*  h1f8 = (unsigned char*)(ws + o_h1f8);
    unsigned short* h1o  = (unsigned short*)(ws + o_h1o);
    float* als1   = (float*)(ws + o_als1);
    float* ald1   = (float*)(ws + o_ald1);
    float* h2lin  = (float*)(ws + o_h2lin);
    float* als2   = (float*)(ws + o_als2);
    float* ald2   = (float*)(ws + o_ald2);
    unsigned short* wb = (unsigned short*)(ws + o_wb);
    unsigned short* xb = (unsigned short*)(ws + o_xb);

    int n16 = (int)(zero_bytes / 16);
    k_zero<<<(n16 + 255) / 256, 256, 0, stream>>>((uint4*)ws, n16);

    int gE = (ETOT + 255) / 256;
    int gW = (NN + 3) / 4;

    k_hist<<<gE, 256, 0, stream>>>(ei, bat, counts, gcount);
    k_scan<<<1, 1024, 0, stream>>>(counts, indptr, cursor);
    k_cvtw<<<128, 256, 0, stream>>>(W1, wb);
    k_cvtx<<<(NN * 128 / 8 + 255) / 256, 256, 0, stream>>>(x, xb);
    k_gemm1<<<(NN + 31) / 32, 256, 0, stream>>>(xb, wb, as1, ad1, h1f8, als1, ald1);
    k_fill<<<gE, 256, 0, stream>>>(ei, cursor, als1, ald1, srcs, dsts, ee1);
    k_gather1<<<gW, 256, 0, stream>>>(indptr, srcs, (const unsigned short*)ee1, h1f8, b1, h1o);
    k_gemm2a<<<gW, 256, 0, stream>>>(h1o, W2, as2, ad2, h2lin, als2, ald2);
    k_ee2<<<gE, 256, 0, stream>>>(srcs, dsts, als2, ald2, ee2);
    k_g2pool<<<gW, 256, 0, stream>>>(indptr, srcs, ee2, h2lin, b2, bat, pooled);
    k_final<<<1, 64, 0, stream>>>(pooled, gcount, out);
    (void)n_in; (void)in_sizes; (void)out_size;
}

// Round 15
// 200.638 us; speedup vs baseline: 1.2537x; 1.1759x over previous
//
#include <hip/hip_runtime.h>
#include <hip/hip_bf16.h>
#include <math.h>

#define NN 50000
#define EE 500000
#define ETOT (EE + NN)
#define NG 64

typedef __attribute__((ext_vector_type(8))) short short8v;   // 8 bf16 (4 VGPRs)
typedef __attribute__((ext_vector_type(4))) float float4v;   // 4 fp32 acc
typedef __attribute__((ext_vector_type(2))) float float2v;

__device__ __forceinline__ float bf2f(unsigned short u) {
    unsigned int v = ((unsigned int)u) << 16;
    return __builtin_bit_cast(float, v);
}
__device__ __forceinline__ unsigned short f2bf(float f) {
    __hip_bfloat16 h = __float2bfloat16(f);
    return *(unsigned short*)&h;
}
__device__ __forceinline__ unsigned char f2fp8_hw(float f) {
    return (unsigned char)(__builtin_amdgcn_cvt_pk_fp8_f32(f, f, 0, false) & 0xff);
}

// ---------------- fused setup: zero scratch + W1->bf16 + x->bf16 ----------
__global__ void k_setup(uint4* __restrict__ zp, int n16, int zB,
                        const float* __restrict__ W1, unsigned short* __restrict__ wb,
                        const float* __restrict__ x, unsigned short* __restrict__ xb) {
    int b = blockIdx.x;
    if (b < zB) {
        int t = b * 256 + threadIdx.x;
        if (t < n16) zp[t] = make_uint4(0, 0, 0, 0);
    } else if (b < zB + 128) {
        int t = (b - zB) * 256 + threadIdx.x;   // 32768 = 128*256 exactly
        wb[t] = f2bf(W1[t]);
    } else {
        int t = (b - zB - 128) * 256 + threadIdx.x;
        if (t < NN * 128 / 8) {
            float4 a = *(const float4*)&x[(size_t)t * 8];
            float4 c = *(const float4*)&x[(size_t)t * 8 + 4];
            float f[8] = {a.x, a.y, a.z, a.w, c.x, c.y, c.z, c.w};
            short8v vh;
#pragma unroll
            for (int j = 0; j < 8; ++j) vh[j] = (short)f2bf(f[j]);
            *(short8v*)&xb[(size_t)t * 8] = vh;
        }
    }
}

// ---------------- histogram of dst + per-graph node counts ----------------
__global__ void k_hist(const int* __restrict__ ei, const int* __restrict__ batch,
                       int* __restrict__ counts, int* __restrict__ gcount) {
    int t = blockIdx.x * 256 + threadIdx.x;
    if (t < ETOT) {
        int dst = (t < EE) ? ei[EE + t] : (t - EE);
        atomicAdd(counts + dst, 1);
    }
    if (t < NN) {
        int g = batch[t];
        int g0 = __shfl(g, 0);
        bool same = (g == g0);
        unsigned long long m = __ballot(same);
        if (same) {
            if ((threadIdx.x & 63) == (__ffsll((long long)m) - 1))
                atomicAdd(gcount + g0, (int)__popcll(m));
        } else {
            atomicAdd(gcount + g, 1);
        }
    }
}

// ---------------- exclusive scan counts -> indptr (+ seed cursor) ---------
// All 13 chunks preloaded upfront (one global latency instead of 13).
__global__ void k_scan(const int* __restrict__ counts, int* __restrict__ indptr,
                       int* __restrict__ cursor) {
    __shared__ int wsum[16];
    __shared__ int carry_s;
    int tid = threadIdx.x;
    int lane = tid & 63;
    int w = tid >> 6;
    int4 v[13];
#pragma unroll
    for (int c = 0; c < 13; ++c) {
        int i = c * 4096 + tid * 4;
        if (i + 3 < NN) {
            v[c] = *(const int4*)&counts[i];
        } else {
            v[c] = make_int4(0, 0, 0, 0);
            if (i < NN) v[c].x = counts[i];
            if (i + 1 < NN) v[c].y = counts[i + 1];
            if (i + 2 < NN) v[c].z = counts[i + 2];
        }
    }
    if (tid == 0) carry_s = 0;
    __syncthreads();
#pragma unroll
    for (int c = 0; c < 13; ++c) {
        int i = c * 4096 + tid * 4;
        int v0 = v[c].x, v1 = v[c].y, v2 = v[c].z, v3 = v[c].w;
        int tot = v0 + v1 + v2 + v3;
        int s = tot;
#pragma unroll
        for (int off = 1; off < 64; off <<= 1) {
            int u = __shfl_up(s, off);
            if (lane >= off) s += u;
        }
        if (lane == 63) wsum[w] = s;
        __syncthreads();
        if (w == 0) {
            int t2 = (lane < 16) ? wsum[lane] : 0;
#pragma unroll
            for (int off = 1; off < 16; off <<= 1) {
                int u = __shfl_up(t2, off);
                if (lane >= off) t2 += u;
            }
            if (lane < 16) wsum[lane] = t2;
        }
        __syncthreads();
        int wpre = (w == 0) ? 0 : wsum[w - 1];
        int incl = s + wpre;
        int carry = carry_s;
        int e = carry + incl - tot;
        if (i < NN)     { indptr[i] = e;            cursor[i] = e; }
        if (i + 1 < NN) { int q = e + v0;           indptr[i+1] = q; cursor[i+1] = q; }
        if (i + 2 < NN) { int q = e + v0 + v1;      indptr[i+2] = q; cursor[i+2] = q; }
        if (i + 3 < NN) { int q = e + v0 + v1 + v2; indptr[i+3] = q; cursor[i+3] = q; }
        __syncthreads();
        if (tid == 1023) carry_s = carry + incl;
        __syncthreads();
    }
    if (tid == 0) indptr[NN] = carry_s;
}

// ---------------- GEMM1 via bf16 MFMA + fused alpha logits ----------------
__global__ __launch_bounds__(256) void k_gemm1(const unsigned short* __restrict__ xb,
                                               const unsigned short* __restrict__ wb,
                                               const float* __restrict__ att_s,
                                               const float* __restrict__ att_d,
                                               unsigned char* __restrict__ h1f8,
                                               float* __restrict__ alpha_s,
                                               float* __restrict__ alpha_d) {
    int w = threadIdx.x >> 6;
    int l = threadIdx.x & 63;
    int bm0 = blockIdx.x * 32;
    int i16 = l & 15;
    int kb = (l >> 4) * 8;
    int colb = w * 64;

    short8v a[2][4];
#pragma unroll
    for (int mi = 0; mi < 2; ++mi) {
        int r = bm0 + mi * 16 + i16;
#pragma unroll
        for (int k = 0; k < 4; ++k) {
            if (r < NN) a[mi][k] = *(const short8v*)&xb[(size_t)r * 128 + k * 32 + kb];
            else        a[mi][k] = (short8v){0,0,0,0,0,0,0,0};
        }
    }

    float4v acc[2][4];
#pragma unroll
    for (int mi = 0; mi < 2; ++mi)
#pragma unroll
        for (int ni = 0; ni < 4; ++ni)
            acc[mi][ni] = (float4v){0.f, 0.f, 0.f, 0.f};

#pragma unroll
    for (int k = 0; k < 4; ++k) {
#pragma unroll
        for (int ni = 0; ni < 4; ++ni) {
            short8v b = *(const short8v*)&wb[(size_t)(colb + ni * 16 + i16) * 128 + k * 32 + kb];
            acc[0][ni] = __builtin_amdgcn_mfma_f32_16x16x32_bf16(a[0][k], b, acc[0][ni], 0, 0, 0);
            acc[1][ni] = __builtin_amdgcn_mfma_f32_16x16x32_bf16(a[1][k], b, acc[1][ni], 0, 0, 0);
        }
    }

    int drb = (l >> 4) * 4;
    int dc = l & 15;
    float asw[4], adw[4];
#pragma unroll
    for (int ni = 0; ni < 4; ++ni) {
        asw[ni] = att_s[colb + ni * 16 + dc];
        adw[ni] = att_d[colb + ni * 16 + dc];
    }
#pragma unroll
    for (int mi = 0; mi < 2; ++mi) {
#pragma unroll
        for (int r = 0; r < 4; ++r) {
            int row = bm0 + mi * 16 + drb + r;
            float s = 0.f, d = 0.f;
#pragma unroll
            for (int ni = 0; ni < 4; ++ni) {
                float v = acc[mi][ni][r];
                s += v * asw[ni];
                d += v * adw[ni];
                if (row < NN)
                    h1f8[(size_t)row * 256 + colb + ni * 16 + dc] = f2fp8_hw(v);
            }
#pragma unroll
            for (int m = 8; m >= 1; m >>= 1) {
                s += __shfl_xor(s, m);
                d += __shfl_xor(d, m);
            }
            if (dc == 0 && row < NN) {
                alpha_s[row * 4 + w] = s;
                alpha_d[row * 4 + w] = d;
            }
        }
    }
}

// ---------------- bucket fill: one 16B edge record per edge ---------------
// edge = {src, ee_heads01 (2x bf16), ee_heads23 (2x bf16), dst}
__global__ void k_fill(const int* __restrict__ ei, int* __restrict__ cursor,
                       const float* __restrict__ als, const float* __restrict__ ald,
                       uint4* __restrict__ edges) {
    int t = blockIdx.x * 256 + threadIdx.x;
    if (t >= ETOT) return;
    int src = (t < EE) ? ei[t] : (t - EE);
    int dst = (t < EE) ? ei[EE + t] : (t - EE);
    int p = atomicAdd(cursor + dst, 1);
    float4 as = *(const float4*)&als[src * 4];
    float4 ad = *(const float4*)&ald[dst * 4];
    float e0 = as.x + ad.x, e1 = as.y + ad.y, e2 = as.z + ad.z, e3 = as.w + ad.w;
    e0 = e0 > 0.f ? e0 : 0.2f * e0;
    e1 = e1 > 0.f ? e1 : 0.2f * e1;
    e2 = e2 > 0.f ? e2 : 0.2f * e2;
    e3 = e3 > 0.f ? e3 : 0.2f * e3;
    unsigned int ee01 = (unsigned int)f2bf(__expf(e0)) | ((unsigned int)f2bf(__expf(e1)) << 16);
    unsigned int ee23 = (unsigned int)f2bf(__expf(e2)) | ((unsigned int)f2bf(__expf(e3)) << 16);
    edges[p] = make_uint4((unsigned int)src, ee01, ee23, (unsigned int)dst);
}

// ---------------- gather1 + softmax + bias + ELU + fused GEMM2 ------------
// one wave per dst node; lane l owns channels 4l..4l+3 (head = l>>4).
// 8-edge unroll; each edge = 1 uint4 (src+weights) + 1 uint payload load.
// Epilogue computes h2lin row + layer-2 alpha logits in-register.
__global__ void k_gather1(const int* __restrict__ indptr, const uint4* __restrict__ edges,
                          const unsigned char* __restrict__ h1f8, const float* __restrict__ b1,
                          const float* __restrict__ W2, const float* __restrict__ as2v,
                          const float* __restrict__ ad2v, float* __restrict__ h2lin,
                          float* __restrict__ als2, float* __restrict__ ald2) {
    int wid = (blockIdx.x * 256 + threadIdx.x) >> 6;
    int l = threadIdx.x & 63;
    if (wid >= NN) return;
    int p0 = __builtin_amdgcn_readfirstlane(indptr[wid]);
    int p1 = __builtin_amdgcn_readfirstlane(indptr[wid + 1]);
    int head = l >> 4;
    int hsh = (head & 1) * 16;
    float acc0 = 0.f, acc1 = 0.f, acc2 = 0.f, acc3 = 0.f, dsum = 0.f;
    int p = p0;
    for (; p + 7 < p1; p += 8) {
        uint4 e[8];
#pragma unroll
        for (int j = 0; j < 8; ++j) e[j] = edges[p + j];
        unsigned int hv[8];
#pragma unroll
        for (int j = 0; j < 8; ++j)
            hv[j] = *(const unsigned int*)&h1f8[(size_t)e[j].x * 256 + l * 4];
#pragma unroll
        for (int j = 0; j < 8; ++j) {
            unsigned int packed = (head & 2) ? e[j].z : e[j].y;
            float wgt = bf2f((unsigned short)(packed >> hsh));
            float2v lo = __builtin_amdgcn_cvt_pk_f32_fp8(hv[j], false);
            float2v hi = __builtin_amdgcn_cvt_pk_f32_fp8(hv[j], true);
            dsum += wgt;
            acc0 += wgt * lo.x;
            acc1 += wgt * lo.y;
            acc2 += wgt * hi.x;
            acc3 += wgt * hi.y;
        }
    }
    for (; p < p1; ++p) {
        uint4 e = edges[p];
        unsigned int hv = *(const unsigned int*)&h1f8[(size_t)e.x * 256 + l * 4];
        unsigned int packed = (head & 2) ? e.z : e.y;
        float wgt = bf2f((unsigned short)(packed >> hsh));
        float2v lo = __builtin_amdgcn_cvt_pk_f32_fp8(hv, false);
        float2v hi = __builtin_amdgcn_cvt_pk_f32_fp8(hv, true);
        dsum += wgt;
        acc0 += wgt * lo.x;
        acc1 += wgt * lo.y;
        acc2 += wgt * hi.x;
        acc3 += wgt * hi.y;
    }
    float inv = 1.0f / dsum;
    float4 bv = *(const float4*)&b1[l * 4];
    float o0 = acc0 * inv + bv.x;
    float o1 = acc1 * inv + bv.y;
    float o2 = acc2 * inv + bv.z;
    float o3 = acc3 * inv + bv.w;
    o0 = o0 > 0.f ? o0 : expm1f(o0);
    o1 = o1 > 0.f ? o1 : expm1f(o1);
    o2 = o2 > 0.f ? o2 : expm1f(o2);
    o3 = o3 > 0.f ? o3 : expm1f(o3);
    // fused GEMM2: t[o] = sum_c h[c]*W2[o][c]  (h in registers across wave)
    float t[10];
#pragma unroll
    for (int o = 0; o < 10; ++o) {
        float4 wv = *(const float4*)&W2[o * 256 + l * 4];
        t[o] = o0 * wv.x + o1 * wv.y + o2 * wv.z + o3 * wv.w;
    }
#pragma unroll
    for (int m = 32; m > 0; m >>= 1) {
#pragma unroll
        for (int o = 0; o < 10; ++o) t[o] += __shfl_xor(t[o], m);
    }
    if (l == 0) {
        float as = 0.f, ad = 0.f;
#pragma unroll
        for (int o = 0; o < 10; ++o) {
            h2lin[(size_t)wid * 16 + o] = t[o];
            as += t[o] * as2v[o];
            ad += t[o] * ad2v[o];
        }
        als2[wid] = as;
        ald2[wid] = ad;
    }
}

// ---------------- gather layer 2 (inline edge weights) + mean-pool --------
// 16-lane group per node (4 nodes/wave); lane c<10 owns channel c.
__global__ void k_g2pool(const int* __restrict__ indptr, const uint4* __restrict__ edges,
                         const float* __restrict__ als2, const float* __restrict__ ald2,
                         const float* __restrict__ h2lin, const float* __restrict__ b2,
                         const int* __restrict__ batch, float* __restrict__ pooled) {
    int wave = (blockIdx.x * 256 + threadIdx.x) >> 6;
    int lane = threadIdx.x & 63;
    int grp = lane >> 4, c = lane & 15;
    int node = wave * 4 + grp;
    float acc = 0.f;
    int g = -1;
    if (node < NN) {
        int p0 = indptr[node], p1 = indptr[node + 1];
        float ad2n = ald2[node];
        float dsum = 0.f;
        for (int p = p0; p < p1; ++p) {
            uint4 e = edges[p];
            float v = als2[e.x] + ad2n;
            v = v > 0.f ? v : 0.2f * v;
            float w = __expf(v);
            dsum += w;
            if (c < 10) acc += w * h2lin[(size_t)e.x * 16 + c];
        }
        if (c < 10) acc = acc / dsum + b2[c];
        else acc = 0.f;
        g = batch[node];
    }
    int g0 = __shfl(g, 0);
    bool uni = __all((node >= NN) || (g == g0));
    if (uni) {
        if (g0 >= 0) {
            acc += __shfl_xor(acc, 16);
            acc += __shfl_xor(acc, 32);
            if (grp == 0 && c < 10)
                atomicAdd(pooled + g0 * 10 + c, acc);
        }
    } else if (node < NN && c < 10) {
        atomicAdd(pooled + g * 10 + c, acc);
    }
}

// ---------------- mean + log_softmax --------------------------------------
__global__ void k_final(const float* __restrict__ pooled, const int* __restrict__ gcount,
                        float* __restrict__ out) {
    int g = threadIdx.x;
    if (g >= NG) return;
    float c = fmaxf((float)gcount[g], 1.0f);
    float m[10];
    float mx = -1e30f;
#pragma unroll
    for (int i = 0; i < 10; ++i) {
        m[i] = pooled[g * 10 + i] / c;
        mx = fmaxf(mx, m[i]);
    }
    float s = 0.f;
#pragma unroll
    for (int i = 0; i < 10; ++i) s += expf(m[i] - mx);
    float lse = mx + logf(s);
#pragma unroll
    for (int i = 0; i < 10; ++i) out[g * 10 + i] = m[i] - lse;
}

extern "C" void kernel_launch(void* const* d_in, const int* in_sizes, int n_in,
                              void* d_out, int out_size, void* d_ws, size_t ws_size,
                              hipStream_t stream) {
    const float* x   = (const float*)d_in[0];
    const int*   ei  = (const int*)d_in[1];
    const int*   bat = (const int*)d_in[3];
    const float* W1  = (const float*)d_in[4];
    const float* as1 = (const float*)d_in[5];
    const float* ad1 = (const float*)d_in[6];
    const float* b1  = (const float*)d_in[7];
    const float* W2  = (const float*)d_in[8];
    const float* as2 = (const float*)d_in[9];
    const float* ad2 = (const float*)d_in[10];
    const float* b2  = (const float*)d_in[11];
    float* out = (float*)d_out;

    char* ws = (char*)d_ws;
    size_t off = 0;
    auto alloc = [&](size_t bytes) -> size_t {
        size_t o = off;
        off = (off + bytes + 255) & ~(size_t)255;
        return o;
    };
    size_t o_counts = alloc((size_t)NN * 4);
    size_t o_pooled = alloc((size_t)NG * 10 * 4);
    size_t o_gcount = alloc((size_t)NG * 4);
    size_t zero_bytes = off;
    size_t o_cursor = alloc((size_t)NN * 4);
    size_t o_indptr = alloc((size_t)(NN + 1) * 4);
    size_t o_edges  = alloc((size_t)ETOT * 16);
    size_t o_h1f8   = alloc((size_t)NN * 256);
    size_t o_als1   = alloc((size_t)NN * 4 * 4);
    size_t o_ald1   = alloc((size_t)NN * 4 * 4);
    size_t o_h2lin  = alloc((size_t)NN * 16 * 4);
    size_t o_als2   = alloc((size_t)NN * 4);
    size_t o_ald2   = alloc((size_t)NN * 4);
    size_t o_wb     = alloc((size_t)256 * 128 * 2);
    size_t o_xb     = alloc((size_t)NN * 128 * 2);
    (void)ws_size;

    int*   counts = (int*)(ws + o_counts);
    float* pooled = (float*)(ws + o_pooled);
    int*   gcount = (int*)(ws + o_gcount);
    int*   cursor = (int*)(ws + o_cursor);
    int*   indptr = (int*)(ws + o_indptr);
    uint4* edges  = (uint4*)(ws + o_edges);
    unsigned char*  h1f8 = (unsigned char*)(ws + o_h1f8);
    float* als1   = (float*)(ws + o_als1);
    float* ald1   = (float*)(ws + o_ald1);
    float* h2lin  = (float*)(ws + o_h2lin);
    float* als2   = (float*)(ws + o_als2);
    float* ald2   = (float*)(ws + o_ald2);
    unsigned short* wb = (unsigned short*)(ws + o_wb);
    unsigned short* xb = (unsigned short*)(ws + o_xb);

    int n16 = (int)(zero_bytes / 16);
    int zB = (n16 + 255) / 256;
    int xB = (NN * 128 / 8 + 255) / 256;   // 3125
    int gE = (ETOT + 255) / 256;
    int gW = (NN + 3) / 4;

    k_setup<<<zB + 128 + xB, 256, 0, stream>>>((uint4*)ws, n16, zB, W1, wb, x, xb);
    k_hist<<<gE, 256, 0, stream>>>(ei, bat, counts, gcount);
    k_scan<<<1, 1024, 0, stream>>>(counts, indptr, cursor);
    k_gemm1<<<(NN + 31) / 32, 256, 0, stream>>>(xb, wb, as1, ad1, h1f8, als1, ald1);
    k_fill<<<gE, 256, 0, stream>>>(ei, cursor, als1, ald1, edges);
    k_gather1<<<gW, 256, 0, stream>>>(indptr, edges, h1f8, b1, W2, as2, ad2,
                                      h2lin, als2, ald2);
    k_g2pool<<<gW, 256, 0, stream>>>(indptr, edges, als2, ald2, h2lin, b2, bat, pooled);
    k_final<<<1, 64, 0, stream>>>(pooled, gcount, out);
    (void)n_in; (void)in_sizes; (void)out_size;
}

// Round 16
// 176.077 us; speedup vs baseline: 1.4285x; 1.1395x over previous
//
#include <hip/hip_runtime.h>
#include <hip/hip_bf16.h>
#include <math.h>

#define NN 50000
#define EE 500000
#define ETOT (EE + NN)
#define NG 64

typedef __attribute__((ext_vector_type(8))) short short8v;   // 8 bf16 (4 VGPRs)
typedef __attribute__((ext_vector_type(4))) float float4v;   // 4 fp32 acc
typedef __attribute__((ext_vector_type(2))) float float2v;

__device__ __forceinline__ float bf2f(unsigned short u) {
    unsigned int v = ((unsigned int)u) << 16;
    return __builtin_bit_cast(float, v);
}
__device__ __forceinline__ unsigned short f2bf(float f) {
    __hip_bfloat16 h = __float2bfloat16(f);
    return *(unsigned short*)&h;
}
__device__ __forceinline__ unsigned char f2fp8_hw(float f) {
    return (unsigned char)(__builtin_amdgcn_cvt_pk_fp8_f32(f, f, 0, false) & 0xff);
}

// ---------------- fused setup: zero scratch + W1->bf16 + x->bf16 ----------
__global__ void k_setup(uint4* __restrict__ zp, int n16, int zB,
                        const float* __restrict__ W1, unsigned short* __restrict__ wb,
                        const float* __restrict__ x, unsigned short* __restrict__ xb) {
    int b = blockIdx.x;
    if (b < zB) {
        int t = b * 256 + threadIdx.x;
        if (t < n16) zp[t] = make_uint4(0, 0, 0, 0);
    } else if (b < zB + 128) {
        int t = (b - zB) * 256 + threadIdx.x;   // 32768 = 128*256 exactly
        wb[t] = f2bf(W1[t]);
    } else {
        int t = (b - zB - 128) * 256 + threadIdx.x;
        if (t < NN * 128 / 8) {
            float4 a = *(const float4*)&x[(size_t)t * 8];
            float4 c = *(const float4*)&x[(size_t)t * 8 + 4];
            float f[8] = {a.x, a.y, a.z, a.w, c.x, c.y, c.z, c.w};
            short8v vh;
#pragma unroll
            for (int j = 0; j < 8; ++j) vh[j] = (short)f2bf(f[j]);
            *(short8v*)&xb[(size_t)t * 8] = vh;
        }
    }
}

// ---------------- histogram of dst + edge ordinal + graph counts ----------
// The atomic's return value IS the edge's within-dst ordinal -> saved so
// k_fill needs no second atomic pass.
__global__ void k_hist(const int* __restrict__ ei, const int* __restrict__ batch,
                       int* __restrict__ counts, int* __restrict__ ord,
                       int* __restrict__ gcount) {
    int t = blockIdx.x * 256 + threadIdx.x;
    if (t < ETOT) {
        int dst = (t < EE) ? ei[EE + t] : (t - EE);
        ord[t] = atomicAdd(counts + dst, 1);
    }
    if (t < NN) {
        int g = batch[t];
        int g0 = __shfl(g, 0);
        bool same = (g == g0);
        unsigned long long m = __ballot(same);
        if (same) {
            if ((threadIdx.x & 63) == (__ffsll((long long)m) - 1))
                atomicAdd(gcount + g0, (int)__popcll(m));
        } else {
            atomicAdd(gcount + g, 1);
        }
    }
}

// ---------------- exclusive scan counts -> indptr -------------------------
// All 13 chunks preloaded upfront (one global latency instead of 13).
__global__ void k_scan(const int* __restrict__ counts, int* __restrict__ indptr) {
    __shared__ int wsum[16];
    __shared__ int carry_s;
    int tid = threadIdx.x;
    int lane = tid & 63;
    int w = tid >> 6;
    int4 v[13];
#pragma unroll
    for (int c = 0; c < 13; ++c) {
        int i = c * 4096 + tid * 4;
        if (i + 3 < NN) {
            v[c] = *(const int4*)&counts[i];
        } else {
            v[c] = make_int4(0, 0, 0, 0);
            if (i < NN) v[c].x = counts[i];
            if (i + 1 < NN) v[c].y = counts[i + 1];
            if (i + 2 < NN) v[c].z = counts[i + 2];
        }
    }
    if (tid == 0) carry_s = 0;
    __syncthreads();
#pragma unroll
    for (int c = 0; c < 13; ++c) {
        int i = c * 4096 + tid * 4;
        int v0 = v[c].x, v1 = v[c].y, v2 = v[c].z, v3 = v[c].w;
        int tot = v0 + v1 + v2 + v3;
        int s = tot;
#pragma unroll
        for (int off = 1; off < 64; off <<= 1) {
            int u = __shfl_up(s, off);
            if (lane >= off) s += u;
        }
        if (lane == 63) wsum[w] = s;
        __syncthreads();
        if (w == 0) {
            int t2 = (lane < 16) ? wsum[lane] : 0;
#pragma unroll
            for (int off = 1; off < 16; off <<= 1) {
                int u = __shfl_up(t2, off);
                if (lane >= off) t2 += u;
            }
            if (lane < 16) wsum[lane] = t2;
        }
        __syncthreads();
        int wpre = (w == 0) ? 0 : wsum[w - 1];
        int incl = s + wpre;
        int carry = carry_s;
        int e = carry + incl - tot;
        if (i < NN)     indptr[i] = e;
        if (i + 1 < NN) indptr[i + 1] = e + v0;
        if (i + 2 < NN) indptr[i + 2] = e + v0 + v1;
        if (i + 3 < NN) indptr[i + 3] = e + v0 + v1 + v2;
        __syncthreads();
        if (tid == 1023) carry_s = carry + incl;
        __syncthreads();
    }
    if (tid == 0) indptr[NN] = carry_s;
}

// ---------------- GEMM1 via bf16 MFMA + fused alpha logits ----------------
__global__ __launch_bounds__(256) void k_gemm1(const unsigned short* __restrict__ xb,
                                               const unsigned short* __restrict__ wb,
                                               const float* __restrict__ att_s,
                                               const float* __restrict__ att_d,
                                               unsigned char* __restrict__ h1f8,
                                               float* __restrict__ alpha_s,
                                               float* __restrict__ alpha_d) {
    int w = threadIdx.x >> 6;
    int l = threadIdx.x & 63;
    int bm0 = blockIdx.x * 32;
    int i16 = l & 15;
    int kb = (l >> 4) * 8;
    int colb = w * 64;

    short8v a[2][4];
#pragma unroll
    for (int mi = 0; mi < 2; ++mi) {
        int r = bm0 + mi * 16 + i16;
#pragma unroll
        for (int k = 0; k < 4; ++k) {
            if (r < NN) a[mi][k] = *(const short8v*)&xb[(size_t)r * 128 + k * 32 + kb];
            else        a[mi][k] = (short8v){0,0,0,0,0,0,0,0};
        }
    }

    float4v acc[2][4];
#pragma unroll
    for (int mi = 0; mi < 2; ++mi)
#pragma unroll
        for (int ni = 0; ni < 4; ++ni)
            acc[mi][ni] = (float4v){0.f, 0.f, 0.f, 0.f};

#pragma unroll
    for (int k = 0; k < 4; ++k) {
#pragma unroll
        for (int ni = 0; ni < 4; ++ni) {
            short8v b = *(const short8v*)&wb[(size_t)(colb + ni * 16 + i16) * 128 + k * 32 + kb];
            acc[0][ni] = __builtin_amdgcn_mfma_f32_16x16x32_bf16(a[0][k], b, acc[0][ni], 0, 0, 0);
            acc[1][ni] = __builtin_amdgcn_mfma_f32_16x16x32_bf16(a[1][k], b, acc[1][ni], 0, 0, 0);
        }
    }

    int drb = (l >> 4) * 4;
    int dc = l & 15;
    float asw[4], adw[4];
#pragma unroll
    for (int ni = 0; ni < 4; ++ni) {
        asw[ni] = att_s[colb + ni * 16 + dc];
        adw[ni] = att_d[colb + ni * 16 + dc];
    }
#pragma unroll
    for (int mi = 0; mi < 2; ++mi) {
#pragma unroll
        for (int r = 0; r < 4; ++r) {
            int row = bm0 + mi * 16 + drb + r;
            float s = 0.f, d = 0.f;
#pragma unroll
            for (int ni = 0; ni < 4; ++ni) {
                float v = acc[mi][ni][r];
                s += v * asw[ni];
                d += v * adw[ni];
                if (row < NN)
                    h1f8[(size_t)row * 256 + colb + ni * 16 + dc] = f2fp8_hw(v);
            }
#pragma unroll
            for (int m = 8; m >= 1; m >>= 1) {
                s += __shfl_xor(s, m);
                d += __shfl_xor(d, m);
            }
            if (dc == 0 && row < NN) {
                alpha_s[row * 4 + w] = s;
                alpha_d[row * 4 + w] = d;
            }
        }
    }
}

// ---------------- bucket fill (no atomic): p = indptr[dst] + ord[t] -------
// edge = {src, ee_heads01 (2x bf16), ee_heads23 (2x bf16), dst}
__global__ void k_fill(const int* __restrict__ ei, const int* __restrict__ indptr,
                       const int* __restrict__ ord,
                       const float* __restrict__ als, const float* __restrict__ ald,
                       uint4* __restrict__ edges) {
    int t = blockIdx.x * 256 + threadIdx.x;
    if (t >= ETOT) return;
    int src = (t < EE) ? ei[t] : (t - EE);
    int dst = (t < EE) ? ei[EE + t] : (t - EE);
    int p = indptr[dst] + ord[t];
    float4 as = *(const float4*)&als[src * 4];
    float4 ad = *(const float4*)&ald[dst * 4];
    float e0 = as.x + ad.x, e1 = as.y + ad.y, e2 = as.z + ad.z, e3 = as.w + ad.w;
    e0 = e0 > 0.f ? e0 : 0.2f * e0;
    e1 = e1 > 0.f ? e1 : 0.2f * e1;
    e2 = e2 > 0.f ? e2 : 0.2f * e2;
    e3 = e3 > 0.f ? e3 : 0.2f * e3;
    unsigned int ee01 = (unsigned int)f2bf(__expf(e0)) | ((unsigned int)f2bf(__expf(e1)) << 16);
    unsigned int ee23 = (unsigned int)f2bf(__expf(e2)) | ((unsigned int)f2bf(__expf(e3)) << 16);
    edges[p] = make_uint4((unsigned int)src, ee01, ee23, (unsigned int)dst);
}

// ---------------- gather1 + softmax + bias + ELU + fused GEMM2 ------------
__global__ void k_gather1(const int* __restrict__ indptr, const uint4* __restrict__ edges,
                          const unsigned char* __restrict__ h1f8, const float* __restrict__ b1,
                          const float* __restrict__ W2, const float* __restrict__ as2v,
                          const float* __restrict__ ad2v, float* __restrict__ h2lin,
                          float* __restrict__ als2, float* __restrict__ ald2) {
    int wid = (blockIdx.x * 256 + threadIdx.x) >> 6;
    int l = threadIdx.x & 63;
    if (wid >= NN) return;
    int p0 = __builtin_amdgcn_readfirstlane(indptr[wid]);
    int p1 = __builtin_amdgcn_readfirstlane(indptr[wid + 1]);
    int head = l >> 4;
    int hsh = (head & 1) * 16;
    float acc0 = 0.f, acc1 = 0.f, acc2 = 0.f, acc3 = 0.f, dsum = 0.f;
    int p = p0;
    for (; p + 7 < p1; p += 8) {
        uint4 e[8];
#pragma unroll
        for (int j = 0; j < 8; ++j) e[j] = edges[p + j];
        unsigned int hv[8];
#pragma unroll
        for (int j = 0; j < 8; ++j)
            hv[j] = *(const unsigned int*)&h1f8[(size_t)e[j].x * 256 + l * 4];
#pragma unroll
        for (int j = 0; j < 8; ++j) {
            unsigned int packed = (head & 2) ? e[j].z : e[j].y;
            float wgt = bf2f((unsigned short)(packed >> hsh));
            float2v lo = __builtin_amdgcn_cvt_pk_f32_fp8(hv[j], false);
            float2v hi = __builtin_amdgcn_cvt_pk_f32_fp8(hv[j], true);
            dsum += wgt;
            acc0 += wgt * lo.x;
            acc1 += wgt * lo.y;
            acc2 += wgt * hi.x;
            acc3 += wgt * hi.y;
        }
    }
    for (; p < p1; ++p) {
        uint4 e = edges[p];
        unsigned int hv = *(const unsigned int*)&h1f8[(size_t)e.x * 256 + l * 4];
        unsigned int packed = (head & 2) ? e.z : e.y;
        float wgt = bf2f((unsigned short)(packed >> hsh));
        float2v lo = __builtin_amdgcn_cvt_pk_f32_fp8(hv, false);
        float2v hi = __builtin_amdgcn_cvt_pk_f32_fp8(hv, true);
        dsum += wgt;
        acc0 += wgt * lo.x;
        acc1 += wgt * lo.y;
        acc2 += wgt * hi.x;
        acc3 += wgt * hi.y;
    }
    float inv = 1.0f / dsum;
    float4 bv = *(const float4*)&b1[l * 4];
    float o0 = acc0 * inv + bv.x;
    float o1 = acc1 * inv + bv.y;
    float o2 = acc2 * inv + bv.z;
    float o3 = acc3 * inv + bv.w;
    o0 = o0 > 0.f ? o0 : expm1f(o0);
    o1 = o1 > 0.f ? o1 : expm1f(o1);
    o2 = o2 > 0.f ? o2 : expm1f(o2);
    o3 = o3 > 0.f ? o3 : expm1f(o3);
    // fused GEMM2: t[o] = sum_c h[c]*W2[o][c]  (h in registers across wave)
    float t[10];
#pragma unroll
    for (int o = 0; o < 10; ++o) {
        float4 wv = *(const float4*)&W2[o * 256 + l * 4];
        t[o] = o0 * wv.x + o1 * wv.y + o2 * wv.z + o3 * wv.w;
    }
#pragma unroll
    for (int m = 32; m > 0; m >>= 1) {
#pragma unroll
        for (int o = 0; o < 10; ++o) t[o] += __shfl_xor(t[o], m);
    }
    if (l == 0) {
        float as = 0.f, ad = 0.f;
#pragma unroll
        for (int o = 0; o < 10; ++o) {
            h2lin[(size_t)wid * 16 + o] = t[o];
            as += t[o] * as2v[o];
            ad += t[o] * ad2v[o];
        }
        als2[wid] = as;
        ald2[wid] = ad;
    }
}

// ---------------- gather layer 2 (inline weights, 4-edge unroll) + pool ---
// 16-lane group per node (4 nodes/wave); lane c<10 owns channel c.
__global__ void k_g2pool(const int* __restrict__ indptr, const uint4* __restrict__ edges,
                         const float* __restrict__ als2, const float* __restrict__ ald2,
                         const float* __restrict__ h2lin, const float* __restrict__ b2,
                         const int* __restrict__ batch, float* __restrict__ pooled) {
    int wave = (blockIdx.x * 256 + threadIdx.x) >> 6;
    int lane = threadIdx.x & 63;
    int grp = lane >> 4, c = lane & 15;
    int node = wave * 4 + grp;
    float acc = 0.f;
    int g = -1;
    if (node < NN) {
        int p0 = indptr[node], p1 = indptr[node + 1];
        float ad2n = ald2[node];
        float dsum = 0.f;
        int p = p0;
        for (; p + 3 < p1; p += 4) {
            uint4 e0 = edges[p], e1 = edges[p + 1], e2 = edges[p + 2], e3 = edges[p + 3];
            float v0 = als2[e0.x] + ad2n;
            float v1 = als2[e1.x] + ad2n;
            float v2 = als2[e2.x] + ad2n;
            float v3 = als2[e3.x] + ad2n;
            float h0 = 0.f, h1_ = 0.f, h2 = 0.f, h3 = 0.f;
            if (c < 10) {
                h0 = h2lin[(size_t)e0.x * 16 + c];
                h1_ = h2lin[(size_t)e1.x * 16 + c];
                h2 = h2lin[(size_t)e2.x * 16 + c];
                h3 = h2lin[(size_t)e3.x * 16 + c];
            }
            v0 = v0 > 0.f ? v0 : 0.2f * v0;
            v1 = v1 > 0.f ? v1 : 0.2f * v1;
            v2 = v2 > 0.f ? v2 : 0.2f * v2;
            v3 = v3 > 0.f ? v3 : 0.2f * v3;
            float w0 = __expf(v0), w1 = __expf(v1), w2 = __expf(v2), w3 = __expf(v3);
            dsum += (w0 + w1) + (w2 + w3);
            acc += w0 * h0 + w1 * h1_ + w2 * h2 + w3 * h3;
        }
        for (; p < p1; ++p) {
            uint4 e = edges[p];
            float v = als2[e.x] + ad2n;
            v = v > 0.f ? v : 0.2f * v;
            float w = __expf(v);
            dsum += w;
            if (c < 10) acc += w * h2lin[(size_t)e.x * 16 + c];
        }
        if (c < 10) acc = acc / dsum + b2[c];
        else acc = 0.f;
        g = batch[node];
    }
    int g0 = __shfl(g, 0);
    bool uni = __all((node >= NN) || (g == g0));
    if (uni) {
        if (g0 >= 0) {
            acc += __shfl_xor(acc, 16);
            acc += __shfl_xor(acc, 32);
            if (grp == 0 && c < 10)
                atomicAdd(pooled + g0 * 10 + c, acc);
        }
    } else if (node < NN && c < 10) {
        atomicAdd(pooled + g * 10 + c, acc);
    }
}

// ---------------- mean + log_softmax --------------------------------------
__global__ void k_final(const float* __restrict__ pooled, const int* __restrict__ gcount,
                        float* __restrict__ out) {
    int g = threadIdx.x;
    if (g >= NG) return;
    float c = fmaxf((float)gcount[g], 1.0f);
    float m[10];
    float mx = -1e30f;
#pragma unroll
    for (int i = 0; i < 10; ++i) {
        m[i] = pooled[g * 10 + i] / c;
        mx = fmaxf(mx, m[i]);
    }
    float s = 0.f;
#pragma unroll
    for (int i = 0; i < 10; ++i) s += expf(m[i] - mx);
    float lse = mx + logf(s);
#pragma unroll
    for (int i = 0; i < 10; ++i) out[g * 10 + i] = m[i] - lse;
}

extern "C" void kernel_launch(void* const* d_in, const int* in_sizes, int n_in,
                              void* d_out, int out_size, void* d_ws, size_t ws_size,
                              hipStream_t stream) {
    const float* x   = (const float*)d_in[0];
    const int*   ei  = (const int*)d_in[1];
    const int*   bat = (const int*)d_in[3];
    const float* W1  = (const float*)d_in[4];
    const float* as1 = (const float*)d_in[5];
    const float* ad1 = (const float*)d_in[6];
    const float* b1  = (const float*)d_in[7];
    const float* W2  = (const float*)d_in[8];
    const float* as2 = (const float*)d_in[9];
    const float* ad2 = (const float*)d_in[10];
    const float* b2  = (const float*)d_in[11];
    float* out = (float*)d_out;

    char* ws = (char*)d_ws;
    size_t off = 0;
    auto alloc = [&](size_t bytes) -> size_t {
        size_t o = off;
        off = (off + bytes + 255) & ~(size_t)255;
        return o;
    };
    size_t o_counts = alloc((size_t)NN * 4);
    size_t o_pooled = alloc((size_t)NG * 10 * 4);
    size_t o_gcount = alloc((size_t)NG * 4);
    size_t zero_bytes = off;
    size_t o_ord    = alloc((size_t)ETOT * 4);
    size_t o_indptr = alloc((size_t)(NN + 1) * 4);
    size_t o_edges  = alloc((size_t)ETOT * 16);
    size_t o_h1f8   = alloc((size_t)NN * 256);
    size_t o_als1   = alloc((size_t)NN * 4 * 4);
    size_t o_ald1   = alloc((size_t)NN * 4 * 4);
    size_t o_h2lin  = alloc((size_t)NN * 16 * 4);
    size_t o_als2   = alloc((size_t)NN * 4);
    size_t o_ald2   = alloc((size_t)NN * 4);
    size_t o_wb     = alloc((size_t)256 * 128 * 2);
    size_t o_xb     = alloc((size_t)NN * 128 * 2);
    (void)ws_size;

    int*   counts = (int*)(ws + o_counts);
    float* pooled = (float*)(ws + o_pooled);
    int*   gcount = (int*)(ws + o_gcount);
    int*   ord    = (int*)(ws + o_ord);
    int*   indptr = (int*)(ws + o_indptr);
    uint4* edges  = (uint4*)(ws + o_edges);
    unsigned char*  h1f8 = (unsigned char*)(ws + o_h1f8);
    float* als1   = (float*)(ws + o_als1);
    float* ald1   = (float*)(ws + o_ald1);
    float* h2lin  = (float*)(ws + o_h2lin);
    float* als2   = (float*)(ws + o_als2);
    float* ald2   = (float*)(ws + o_ald2);
    unsigned short* wb = (unsigned short*)(ws + o_wb);
    unsigned short* xb = (unsigned short*)(ws + o_xb);

    int n16 = (int)(zero_bytes / 16);
    int zB = (n16 + 255) / 256;
    int xB = (NN * 128 / 8 + 255) / 256;   // 3125
    int gE = (ETOT + 255) / 256;
    int gW = (NN + 3) / 4;

    k_setup<<<zB + 128 + xB, 256, 0, stream>>>((uint4*)ws, n16, zB, W1, wb, x, xb);
    k_hist<<<gE, 256, 0, stream>>>(ei, bat, counts, ord, gcount);
    k_scan<<<1, 1024, 0, stream>>>(counts, indptr);
    k_gemm1<<<(NN + 31) / 32, 256, 0, stream>>>(xb, wb, as1, ad1, h1f8, als1, ald1);
    k_fill<<<gE, 256, 0, stream>>>(ei, indptr, ord, als1, ald1, edges);
    k_gather1<<<gW, 256, 0, stream>>>(indptr, edges, h1f8, b1, W2, as2, ad2,
                                      h2lin, als2, ald2);
    k_g2pool<<<gW, 256, 0, stream>>>(indptr, edges, als2, ald2, h2lin, b2, bat, pooled);
    k_final<<<1, 64, 0, stream>>>(pooled, gcount, out);
    (void)n_in; (void)in_sizes; (void)out_size;
}

// Round 17
// 172.205 us; speedup vs baseline: 1.4607x; 1.0225x over previous
//
#include <hip/hip_runtime.h>
#include <hip/hip_bf16.h>
#include <math.h>

#define NN 50000
#define EE 500000
#define ETOT (EE + NN)
#define NG 64

typedef __attribute__((ext_vector_type(8))) short short8v;   // 8 bf16 (4 VGPRs)
typedef __attribute__((ext_vector_type(4))) float float4v;   // 4 fp32 acc
typedef __attribute__((ext_vector_type(2))) float float2v;

__device__ __forceinline__ float bf2f(unsigned short u) {
    unsigned int v = ((unsigned int)u) << 16;
    return __builtin_bit_cast(float, v);
}
__device__ __forceinline__ unsigned short f2bf(float f) {
    __hip_bfloat16 h = __float2bfloat16(f);
    return *(unsigned short*)&h;
}

// ---------------- fused setup: zero scratch + W1->bf16 + x->bf16 ----------
__global__ void k_setup(uint4* __restrict__ zp, int n16, int zB,
                        const float* __restrict__ W1, unsigned short* __restrict__ wb,
                        const float* __restrict__ x, unsigned short* __restrict__ xb) {
    int b = blockIdx.x;
    if (b < zB) {
        int t = b * 256 + threadIdx.x;
        if (t < n16) zp[t] = make_uint4(0, 0, 0, 0);
    } else if (b < zB + 128) {
        int t = (b - zB) * 256 + threadIdx.x;   // 32768 = 128*256 exactly
        wb[t] = f2bf(W1[t]);
    } else {
        int t = (b - zB - 128) * 256 + threadIdx.x;
        if (t < NN * 128 / 8) {
            float4 a = *(const float4*)&x[(size_t)t * 8];
            float4 c = *(const float4*)&x[(size_t)t * 8 + 4];
            float f[8] = {a.x, a.y, a.z, a.w, c.x, c.y, c.z, c.w};
            short8v vh;
#pragma unroll
            for (int j = 0; j < 8; ++j) vh[j] = (short)f2bf(f[j]);
            *(short8v*)&xb[(size_t)t * 8] = vh;
        }
    }
}

// ---------------- histogram of dst + edge ordinal + graph counts ----------
__global__ void k_hist(const int* __restrict__ ei, const int* __restrict__ batch,
                       int* __restrict__ counts, int* __restrict__ ord,
                       int* __restrict__ gcount) {
    int t = blockIdx.x * 256 + threadIdx.x;
    if (t < ETOT) {
        int dst = (t < EE) ? ei[EE + t] : (t - EE);
        ord[t] = atomicAdd(counts + dst, 1);
    }
    if (t < NN) {
        int g = batch[t];
        int g0 = __shfl(g, 0);
        bool same = (g == g0);
        unsigned long long m = __ballot(same);
        if (same) {
            if ((threadIdx.x & 63) == (__ffsll((long long)m) - 1))
                atomicAdd(gcount + g0, (int)__popcll(m));
        } else {
            atomicAdd(gcount + g, 1);
        }
    }
}

// ---------------- exclusive scan counts -> indptr -------------------------
__global__ void k_scan(const int* __restrict__ counts, int* __restrict__ indptr) {
    __shared__ int wsum[16];
    __shared__ int carry_s;
    int tid = threadIdx.x;
    int lane = tid & 63;
    int w = tid >> 6;
    int4 v[13];
#pragma unroll
    for (int c = 0; c < 13; ++c) {
        int i = c * 4096 + tid * 4;
        if (i + 3 < NN) {
            v[c] = *(const int4*)&counts[i];
        } else {
            v[c] = make_int4(0, 0, 0, 0);
            if (i < NN) v[c].x = counts[i];
            if (i + 1 < NN) v[c].y = counts[i + 1];
            if (i + 2 < NN) v[c].z = counts[i + 2];
        }
    }
    if (tid == 0) carry_s = 0;
    __syncthreads();
#pragma unroll
    for (int c = 0; c < 13; ++c) {
        int i = c * 4096 + tid * 4;
        int v0 = v[c].x, v1 = v[c].y, v2 = v[c].z, v3 = v[c].w;
        int tot = v0 + v1 + v2 + v3;
        int s = tot;
#pragma unroll
        for (int off = 1; off < 64; off <<= 1) {
            int u = __shfl_up(s, off);
            if (lane >= off) s += u;
        }
        if (lane == 63) wsum[w] = s;
        __syncthreads();
        if (w == 0) {
            int t2 = (lane < 16) ? wsum[lane] : 0;
#pragma unroll
            for (int off = 1; off < 16; off <<= 1) {
                int u = __shfl_up(t2, off);
                if (lane >= off) t2 += u;
            }
            if (lane < 16) wsum[lane] = t2;
        }
        __syncthreads();
        int wpre = (w == 0) ? 0 : wsum[w - 1];
        int incl = s + wpre;
        int carry = carry_s;
        int e = carry + incl - tot;
        if (i < NN)     indptr[i] = e;
        if (i + 1 < NN) indptr[i + 1] = e + v0;
        if (i + 2 < NN) indptr[i + 2] = e + v0 + v1;
        if (i + 3 < NN) indptr[i + 3] = e + v0 + v1 + v2;
        __syncthreads();
        if (tid == 1023) carry_s = carry + incl;
        __syncthreads();
    }
    if (tid == 0) indptr[NN] = carry_s;
}

// ---------------- GEMM1 via bf16 MFMA + fused alpha logits ----------------
// h1f8 layout (PERMUTED, must match gather1): byte addr = row*256 + head*64
// + dc*4 + ni  (dc = col&15 within head, ni = col>>4 within head).
// Per (mi,r): 4 fp8 packed into ONE uint store via 2x cvt_pk_fp8_f32.
__global__ __launch_bounds__(256) void k_gemm1(const unsigned short* __restrict__ xb,
                                               const unsigned short* __restrict__ wb,
                                               const float* __restrict__ att_s,
                                               const float* __restrict__ att_d,
                                               unsigned char* __restrict__ h1f8,
                                               float* __restrict__ alpha_s,
                                               float* __restrict__ alpha_d) {
    int w = threadIdx.x >> 6;
    int l = threadIdx.x & 63;
    int bm0 = blockIdx.x * 32;
    int i16 = l & 15;
    int kb = (l >> 4) * 8;
    int colb = w * 64;

    short8v a[2][4];
#pragma unroll
    for (int mi = 0; mi < 2; ++mi) {
        int r = bm0 + mi * 16 + i16;
#pragma unroll
        for (int k = 0; k < 4; ++k) {
            if (r < NN) a[mi][k] = *(const short8v*)&xb[(size_t)r * 128 + k * 32 + kb];
            else        a[mi][k] = (short8v){0,0,0,0,0,0,0,0};
        }
    }

    float4v acc[2][4];
#pragma unroll
    for (int mi = 0; mi < 2; ++mi)
#pragma unroll
        for (int ni = 0; ni < 4; ++ni)
            acc[mi][ni] = (float4v){0.f, 0.f, 0.f, 0.f};

#pragma unroll
    for (int k = 0; k < 4; ++k) {
#pragma unroll
        for (int ni = 0; ni < 4; ++ni) {
            short8v b = *(const short8v*)&wb[(size_t)(colb + ni * 16 + i16) * 128 + k * 32 + kb];
            acc[0][ni] = __builtin_amdgcn_mfma_f32_16x16x32_bf16(a[0][k], b, acc[0][ni], 0, 0, 0);
            acc[1][ni] = __builtin_amdgcn_mfma_f32_16x16x32_bf16(a[1][k], b, acc[1][ni], 0, 0, 0);
        }
    }

    int drb = (l >> 4) * 4;
    int dc = l & 15;
    float asw[4], adw[4];
#pragma unroll
    for (int ni = 0; ni < 4; ++ni) {
        asw[ni] = att_s[colb + ni * 16 + dc];
        adw[ni] = att_d[colb + ni * 16 + dc];
    }
#pragma unroll
    for (int mi = 0; mi < 2; ++mi) {
#pragma unroll
        for (int r = 0; r < 4; ++r) {
            int row = bm0 + mi * 16 + drb + r;
            float v0 = acc[mi][0][r], v1 = acc[mi][1][r];
            float v2 = acc[mi][2][r], v3 = acc[mi][3][r];
            float s = v0 * asw[0] + v1 * asw[1] + v2 * asw[2] + v3 * asw[3];
            float d = v0 * adw[0] + v1 * adw[1] + v2 * adw[2] + v3 * adw[3];
            unsigned int packed = __builtin_amdgcn_cvt_pk_fp8_f32(v0, v1, 0u, false);
            packed = __builtin_amdgcn_cvt_pk_fp8_f32(v2, v3, packed, true);
            if (row < NN)
                *(unsigned int*)&h1f8[(size_t)row * 256 + colb + dc * 4] = packed;
#pragma unroll
            for (int m = 8; m >= 1; m >>= 1) {
                s += __shfl_xor(s, m);
                d += __shfl_xor(d, m);
            }
            if (dc == 0 && row < NN) {
                alpha_s[row * 4 + w] = s;
                alpha_d[row * 4 + w] = d;
            }
        }
    }
}

// ---------------- bucket fill (no atomic): p = indptr[dst] + ord[t] -------
__global__ void k_fill(const int* __restrict__ ei, const int* __restrict__ indptr,
                       const int* __restrict__ ord,
                       const float* __restrict__ als, const float* __restrict__ ald,
                       uint4* __restrict__ edges) {
    int t = blockIdx.x * 256 + threadIdx.x;
    if (t >= ETOT) return;
    int src = (t < EE) ? ei[t] : (t - EE);
    int dst = (t < EE) ? ei[EE + t] : (t - EE);
    int p = indptr[dst] + ord[t];
    float4 as = *(const float4*)&als[src * 4];
    float4 ad = *(const float4*)&ald[dst * 4];
    float e0 = as.x + ad.x, e1 = as.y + ad.y, e2 = as.z + ad.z, e3 = as.w + ad.w;
    e0 = e0 > 0.f ? e0 : 0.2f * e0;
    e1 = e1 > 0.f ? e1 : 0.2f * e1;
    e2 = e2 > 0.f ? e2 : 0.2f * e2;
    e3 = e3 > 0.f ? e3 : 0.2f * e3;
    unsigned int ee01 = (unsigned int)f2bf(__expf(e0)) | ((unsigned int)f2bf(__expf(e1)) << 16);
    unsigned int ee23 = (unsigned int)f2bf(__expf(e2)) | ((unsigned int)f2bf(__expf(e3)) << 16);
    edges[p] = make_uint4((unsigned int)src, ee01, ee23, (unsigned int)dst);
}

// ---------------- gather1 + softmax + bias + ELU + fused GEMM2 ------------
// Predicated 8-wide blocks (no serial tail; degree>=1 via self-loop).
// Lane l owns channels c_j = head*64 + j*16 + (l&15), payload = one uint at
// h1f8[src*256 + l*4] (permuted layout written by gemm1).
__global__ void k_gather1(const int* __restrict__ indptr, const uint4* __restrict__ edges,
                          const unsigned char* __restrict__ h1f8, const float* __restrict__ b1,
                          const float* __restrict__ W2, const float* __restrict__ as2v,
                          const float* __restrict__ ad2v, float* __restrict__ h2lin,
                          float* __restrict__ als2, float* __restrict__ ald2) {
    int wid = (blockIdx.x * 256 + threadIdx.x) >> 6;
    int l = threadIdx.x & 63;
    if (wid >= NN) return;
    int p0 = __builtin_amdgcn_readfirstlane(indptr[wid]);
    int p1 = __builtin_amdgcn_readfirstlane(indptr[wid + 1]);
    int last = p1 - 1;
    int head = l >> 4;
    int hsh = (head & 1) * 16;
    const unsigned char* hb = h1f8 + l * 4;
    float acc0 = 0.f, acc1 = 0.f, acc2 = 0.f, acc3 = 0.f, dsum = 0.f;
    for (int p = p0; p < p1; p += 8) {
        uint4 e[8];
#pragma unroll
        for (int j = 0; j < 8; ++j) {
            int idx = p + j;
            e[j] = edges[idx < p1 ? idx : last];
        }
        unsigned int hv[8];
#pragma unroll
        for (int j = 0; j < 8; ++j)
            hv[j] = *(const unsigned int*)(hb + (size_t)e[j].x * 256);
#pragma unroll
        for (int j = 0; j < 8; ++j) {
            unsigned int packed = (head & 2) ? e[j].z : e[j].y;
            float wgt = bf2f((unsigned short)(packed >> hsh));
            wgt = (p + j < p1) ? wgt : 0.f;
            float2v lo = __builtin_amdgcn_cvt_pk_f32_fp8(hv[j], false);
            float2v hi = __builtin_amdgcn_cvt_pk_f32_fp8(hv[j], true);
            dsum += wgt;
            acc0 += wgt * lo.x;
            acc1 += wgt * lo.y;
            acc2 += wgt * hi.x;
            acc3 += wgt * hi.y;
        }
    }
    float inv = 1.0f / dsum;
    int cbase = head * 64 + (l & 15);
    float o0 = acc0 * inv + b1[cbase];
    float o1 = acc1 * inv + b1[cbase + 16];
    float o2 = acc2 * inv + b1[cbase + 32];
    float o3 = acc3 * inv + b1[cbase + 48];
    o0 = o0 > 0.f ? o0 : expm1f(o0);
    o1 = o1 > 0.f ? o1 : expm1f(o1);
    o2 = o2 > 0.f ? o2 : expm1f(o2);
    o3 = o3 > 0.f ? o3 : expm1f(o3);
    // fused GEMM2 over permuted channels
    float t[10];
#pragma unroll
    for (int o = 0; o < 10; ++o) {
        const float* wr = &W2[o * 256 + cbase];
        t[o] = o0 * wr[0] + o1 * wr[16] + o2 * wr[32] + o3 * wr[48];
    }
#pragma unroll
    for (int m = 32; m > 0; m >>= 1) {
#pragma unroll
        for (int o = 0; o < 10; ++o) t[o] += __shfl_xor(t[o], m);
    }
    if (l == 0) {
        float as = 0.f, ad = 0.f;
#pragma unroll
        for (int o = 0; o < 10; ++o) {
            h2lin[(size_t)wid * 16 + o] = t[o];
            as += t[o] * as2v[o];
            ad += t[o] * ad2v[o];
        }
        als2[wid] = as;
        ald2[wid] = ad;
    }
}

// ---------------- gather layer 2 (predicated 4-wide) + mean-pool ----------
__global__ void k_g2pool(const int* __restrict__ indptr, const uint4* __restrict__ edges,
                         const float* __restrict__ als2, const float* __restrict__ ald2,
                         const float* __restrict__ h2lin, const float* __restrict__ b2,
                         const int* __restrict__ batch, float* __restrict__ pooled) {
    int wave = (blockIdx.x * 256 + threadIdx.x) >> 6;
    int lane = threadIdx.x & 63;
    int grp = lane >> 4, c = lane & 15;
    int node = wave * 4 + grp;
    float acc = 0.f;
    int g = -1;
    if (node < NN) {
        int p0 = indptr[node], p1 = indptr[node + 1];
        int last = p1 - 1;
        float ad2n = ald2[node];
        float dsum = 0.f;
        for (int p = p0; p < p1; p += 4) {
            int i0 = p, i1 = p + 1, i2 = p + 2, i3 = p + 3;
            uint4 e0 = edges[i0];
            uint4 e1 = edges[i1 < p1 ? i1 : last];
            uint4 e2 = edges[i2 < p1 ? i2 : last];
            uint4 e3 = edges[i3 < p1 ? i3 : last];
            float v0 = als2[e0.x] + ad2n;
            float v1 = als2[e1.x] + ad2n;
            float v2 = als2[e2.x] + ad2n;
            float v3 = als2[e3.x] + ad2n;
            float h0 = 0.f, h1_ = 0.f, h2 = 0.f, h3 = 0.f;
            if (c < 10) {
                h0 = h2lin[(size_t)e0.x * 16 + c];
                h1_ = h2lin[(size_t)e1.x * 16 + c];
                h2 = h2lin[(size_t)e2.x * 16 + c];
                h3 = h2lin[(size_t)e3.x * 16 + c];
            }
            v0 = v0 > 0.f ? v0 : 0.2f * v0;
            v1 = v1 > 0.f ? v1 : 0.2f * v1;
            v2 = v2 > 0.f ? v2 : 0.2f * v2;
            v3 = v3 > 0.f ? v3 : 0.2f * v3;
            float w0 = __expf(v0);
            float w1 = (i1 < p1) ? __expf(v1) : 0.f;
            float w2 = (i2 < p1) ? __expf(v2) : 0.f;
            float w3 = (i3 < p1) ? __expf(v3) : 0.f;
            dsum += (w0 + w1) + (w2 + w3);
            acc += w0 * h0 + w1 * h1_ + w2 * h2 + w3 * h3;
        }
        if (c < 10) acc = acc / dsum + b2[c];
        else acc = 0.f;
        g = batch[node];
    }
    int g0 = __shfl(g, 0);
    bool uni = __all((node >= NN) || (g == g0));
    if (uni) {
        if (g0 >= 0) {
            acc += __shfl_xor(acc, 16);
            acc += __shfl_xor(acc, 32);
            if (grp == 0 && c < 10)
                atomicAdd(pooled + g0 * 10 + c, acc);
        }
    } else if (node < NN && c < 10) {
        atomicAdd(pooled + g * 10 + c, acc);
    }
}

// ---------------- mean + log_softmax --------------------------------------
__global__ void k_final(const float* __restrict__ pooled, const int* __restrict__ gcount,
                        float* __restrict__ out) {
    int g = threadIdx.x;
    if (g >= NG) return;
    float c = fmaxf((float)gcount[g], 1.0f);
    float m[10];
    float mx = -1e30f;
#pragma unroll
    for (int i = 0; i < 10; ++i) {
        m[i] = pooled[g * 10 + i] / c;
        mx = fmaxf(mx, m[i]);
    }
    float s = 0.f;
#pragma unroll
    for (int i = 0; i < 10; ++i) s += expf(m[i] - mx);
    float lse = mx + logf(s);
#pragma unroll
    for (int i = 0; i < 10; ++i) out[g * 10 + i] = m[i] - lse;
}

extern "C" void kernel_launch(void* const* d_in, const int* in_sizes, int n_in,
                              void* d_out, int out_size, void* d_ws, size_t ws_size,
                              hipStream_t stream) {
    const float* x   = (const float*)d_in[0];
    const int*   ei  = (const int*)d_in[1];
    const int*   bat = (const int*)d_in[3];
    const float* W1  = (const float*)d_in[4];
    const float* as1 = (const float*)d_in[5];
    const float* ad1 = (const float*)d_in[6];
    const float* b1  = (const float*)d_in[7];
    const float* W2  = (const float*)d_in[8];
    const float* as2 = (const float*)d_in[9];
    const float* ad2 = (const float*)d_in[10];
    const float* b2  = (const float*)d_in[11];
    float* out = (float*)d_out;

    char* ws = (char*)d_ws;
    size_t off = 0;
    auto alloc = [&](size_t bytes) -> size_t {
        size_t o = off;
        off = (off + bytes + 255) & ~(size_t)255;
        return o;
    };
    size_t o_counts = alloc((size_t)NN * 4);
    size_t o_pooled = alloc((size_t)NG * 10 * 4);
    size_t o_gcount = alloc((size_t)NG * 4);
    size_t zero_bytes = off;
    size_t o_ord    = alloc((size_t)ETOT * 4);
    size_t o_indptr = alloc((size_t)(NN + 1) * 4);
    size_t o_edges  = alloc((size_t)ETOT * 16);
    size_t o_h1f8   = alloc((size_t)NN * 256);
    size_t o_als1   = alloc((size_t)NN * 4 * 4);
    size_t o_ald1   = alloc((size_t)NN * 4 * 4);
    size_t o_h2lin  = alloc((size_t)NN * 16 * 4);
    size_t o_als2   = alloc((size_t)NN * 4);
    size_t o_ald2   = alloc((size_t)NN * 4);
    size_t o_wb     = alloc((size_t)256 * 128 * 2);
    size_t o_xb     = alloc((size_t)NN * 128 * 2);
    (void)ws_size;

    int*   counts = (int*)(ws + o_counts);
    float* pooled = (float*)(ws + o_pooled);
    int*   gcount = (int*)(ws + o_gcount);
    int*   ord    = (int*)(ws + o_ord);
    int*   indptr = (int*)(ws + o_indptr);
    uint4* edges  = (uint4*)(ws + o_edges);
    unsigned char*  h1f8 = (unsigned char*)(ws + o_h1f8);
    float* als1   = (float*)(ws + o_als1);
    float* ald1   = (float*)(ws + o_ald1);
    float* h2lin  = (float*)(ws + o_h2lin);
    float* als2   = (float*)(ws + o_als2);
    float* ald2   = (float*)(ws + o_ald2);
    unsigned short* wb = (unsigned short*)(ws + o_wb);
    unsigned short* xb = (unsigned short*)(ws + o_xb);

    int n16 = (int)(zero_bytes / 16);
    int zB = (n16 + 255) / 256;
    int xB = (NN * 128 / 8 + 255) / 256;   // 3125
    int gE = (ETOT + 255) / 256;
    int gW = (NN + 3) / 4;

    k_setup<<<zB + 128 + xB, 256, 0, stream>>>((uint4*)ws, n16, zB, W1, wb, x, xb);
    k_hist<<<gE, 256, 0, stream>>>(ei, bat, counts, ord, gcount);
    k_scan<<<1, 1024, 0, stream>>>(counts, indptr);
    k_gemm1<<<(NN + 31) / 32, 256, 0, stream>>>(xb, wb, as1, ad1, h1f8, als1, ald1);
    k_fill<<<gE, 256, 0, stream>>>(ei, indptr, ord, als1, ald1, edges);
    k_gather1<<<gW, 256, 0, stream>>>(indptr, edges, h1f8, b1, W2, as2, ad2,
                                      h2lin, als2, ald2);
    k_g2pool<<<gW, 256, 0, stream>>>(indptr, edges, als2, ald2, h2lin, b2, bat, pooled);
    k_final<<<1, 64, 0, stream>>>(pooled, gcount, out);
    (void)n_in; (void)in_sizes; (void)out_size;
}